// Round 6
// baseline (569.508 us; speedup 1.0000x reference)
//
#include <hip/hip_runtime.h>
#include <cstdint>
#include <cstddef>

#define TT 4
#define BB 4
#define LL 1024
#define CC 256
#define HH 8
#define HD 32
#define NWIN 8
#define WIN 128
#define TOPKN 4
#define C3 768

// ---------------------------------------------------------------------------
// 1. region sums: region[b,n,c] = sum_t sum_r x[t,b,n*128+r,c]
__global__ __launch_bounds__(256) void region_kernel(const float* __restrict__ x,
                                                     float* __restrict__ region) {
    int bn = blockIdx.x;          // b*NWIN + n
    int b = bn >> 3, n = bn & 7;
    int c = threadIdx.x;
    float tot = 0.0f;
    for (int r = 0; r < WIN; ++r) {
        int l = n * WIN + r;
        float s = 0.0f;
        for (int t = 0; t < TT; ++t) {
            s += x[(((size_t)t * BB + b) * LL + l) * CC + c];
        }
        tot += s;
    }
    region[(size_t)bn * CC + c] = tot;
}

// ---------------------------------------------------------------------------
// 2. routing: attn_r[n,m] = dot(region[b,n], region[b,m]) * C^-0.5, top-4 per n
__global__ __launch_bounds__(64) void route_kernel(const float* __restrict__ region,
                                                   int* __restrict__ idx) {
    int b = blockIdx.x;
    __shared__ float reg[NWIN][CC];
    __shared__ float attn_r[NWIN][NWIN];
    int tid = threadIdx.x;
    for (int e = tid; e < NWIN * CC; e += 64)
        reg[e >> 8][e & 255] = region[(size_t)b * NWIN * CC + e];
    __syncthreads();
    int n = tid >> 3, m = tid & 7;
    float s = 0.0f;
    for (int c = 0; c < CC; ++c) s += reg[n][c] * reg[m][c];
    attn_r[n][m] = s * 0.0625f;   // C^-0.5 = 1/16 exact
    __syncthreads();
    if (tid < NWIN) {
        float vals[NWIN];
        for (int m2 = 0; m2 < NWIN; ++m2) vals[m2] = attn_r[tid][m2];
        for (int kk = 0; kk < TOPKN; ++kk) {
            int bi = 0; float bv = vals[0];
            for (int m2 = 1; m2 < NWIN; ++m2) {
                if (vals[m2] > bv) { bv = vals[m2]; bi = m2; }
            }
            idx[(b * NWIN + tid) * TOPKN + kk] = bi;
            vals[bi] = -INFINITY;
        }
    }
}

// ---------------------------------------------------------------------------
// 3. fp32 GEMM + bias (K ascending, exact)
__global__ __launch_bounds__(256) void gemm_bias(const float* __restrict__ A,
                                                 const float* __restrict__ W,
                                                 const float* __restrict__ bias,
                                                 float* __restrict__ C,
                                                 int M, int N, int K) {
    const int BM = 128, BN = 64, BK = 16, TM = 8, TN = 4;
    __shared__ float As[BK][BM + 4];
    __shared__ float Bs[BK][BN];
    int tid = threadIdx.x;
    int tx = tid & 15, ty = tid >> 4;
    int bm = blockIdx.x * BM, bn = blockIdx.y * BN;
    float acc[TM][TN] = {};
    for (int k0 = 0; k0 < K; k0 += BK) {
#pragma unroll
        for (int it = 0; it < 2; ++it) {
            int i = it * 256 + tid;
            int row = i >> 2, kc = (i & 3) * 4;
            float4 v = *(const float4*)(A + (size_t)(bm + row) * K + k0 + kc);
            As[kc + 0][row] = v.x; As[kc + 1][row] = v.y;
            As[kc + 2][row] = v.z; As[kc + 3][row] = v.w;
        }
        {
            int kr = tid >> 4, nc = (tid & 15) * 4;
            float4 v = *(const float4*)(W + (size_t)(k0 + kr) * N + bn + nc);
            *(float4*)&Bs[kr][nc] = v;
        }
        __syncthreads();
#pragma unroll
        for (int kk = 0; kk < BK; ++kk) {
            float a[TM], bb[TN];
            const float4* ap = (const float4*)&As[kk][ty * TM];
            float4 a0 = ap[0], a1 = ap[1];
            a[0]=a0.x; a[1]=a0.y; a[2]=a0.z; a[3]=a0.w;
            a[4]=a1.x; a[5]=a1.y; a[6]=a1.z; a[7]=a1.w;
            float4 b0 = *(const float4*)&Bs[kk][tx * TN];
            bb[0]=b0.x; bb[1]=b0.y; bb[2]=b0.z; bb[3]=b0.w;
#pragma unroll
            for (int i = 0; i < TM; ++i)
#pragma unroll
                for (int j = 0; j < TN; ++j)
                    acc[i][j] = fmaf(a[i], bb[j], acc[i][j]);
        }
        __syncthreads();
    }
#pragma unroll
    for (int i = 0; i < TM; ++i) {
        int row = bm + ty * TM + i;
#pragma unroll
        for (int j = 0; j < TN; ++j) {
            int col = bn + tx * TN + j;
            C[(size_t)row * N + col] = acc[i][j] + bias[col];
        }
    }
}

// ---------------------------------------------------------------------------
// 4. LIF over T
__global__ __launch_bounds__(256) void lif_kernel(const float* src, float* dst, size_t stride) {
    size_t i = ((size_t)blockIdx.x * blockDim.x + threadIdx.x) * 4;
    float v[4] = {0.f, 0.f, 0.f, 0.f};
    for (int t = 0; t < TT; ++t) {
        float4 xv4 = *(const float4*)(src + (size_t)t * stride + i);
        float xv[4] = {xv4.x, xv4.y, xv4.z, xv4.w};
        float sp[4];
#pragma unroll
        for (int j = 0; j < 4; ++j) {
            v[j] = v[j] + (xv[j] - v[j]) * 0.5f;
            bool fire = (v[j] >= 1.0f);
            sp[j] = fire ? 1.0f : 0.0f;
            v[j] = fire ? 0.0f : v[j];
        }
        *(float4*)(dst + (size_t)t * stride + i) = make_float4(sp[0], sp[1], sp[2], sp[3]);
    }
}

// ---------------------------------------------------------------------------
// 4b. pack Q/K spike bits: pk[row][0..7] = q words, pk[row][8..15] = k words
__global__ __launch_bounds__(256) void pack_kernel(const float* __restrict__ spk,
                                                   uint32_t* __restrict__ pk) {
    size_t g = (size_t)blockIdx.x * 256 + threadIdx.x;   // over 16384*512
    int row = (int)(g >> 9);
    int col = (int)(g & 511);
    float v = spk[(size_t)row * C3 + col];
    unsigned long long m = __ballot(v >= 0.5f);
    int lane = threadIdx.x & 63;
    if ((lane & 31) == 0)
        pk[(size_t)row * 16 + (col >> 5)] = (lane < 32) ? (uint32_t)m : (uint32_t)(m >> 32);
}

// ---------------------------------------------------------------------------
// 5. windowed spike attention v6. Block = (t,b,n,hp,dh): 1024 blocks, 256 threads,
//    q=tid&127, h=tid>>7, 16 d-dims per thread. 4-deep register ring for V rows and
//    P values (static indices). Per-d fma chains ascending k -> bitwise exact.
__global__ __launch_bounds__(256, 4) void attn_kernel(const float* __restrict__ spk,
                                                      const uint32_t* __restrict__ pk,
                                                      const int* __restrict__ idxws,
                                                      float* __restrict__ out) {
    int bid = blockIdx.x;
    int dh = bid & 1, hp = (bid >> 1) & 3, n = (bid >> 3) & 7, b = (bid >> 6) & 3, t = bid >> 8;
    __shared__ uint32_t kbs[2][512];
    __shared__ float ptab[33][256];
    int tid = threadIdx.x;
    int q = tid & 127, h = tid >> 7;
    int lbase = (t * BB + b) * LL;

    // route indices -> registers (uniform loads)
    const int* ip = idxws + (b * NWIN + n) * TOPKN;
    int s0r = ip[0], s1r = ip[1], s2r = ip[2], s3r = ip[3];

    // stage gathered K bit-words (both halves)
#pragma unroll 4
    for (int e = tid; e < 1024; e += 256) {
        int hh = e >> 9, kk = e & 511;
        int w = kk >> 7;
        int sw = (w == 0) ? s0r : (w == 1) ? s1r : (w == 2) ? s2r : s3r;
        int row = sw * WIN + (kk & 127);
        kbs[hh][kk] = pk[(size_t)(lbase + row) * 16 + 8 + hp * 2 + hh];
    }
    uint32_t qw = pk[(size_t)(lbase + n * WIN + q) * 16 + hp * 2 + h];
    __syncthreads();

    const float ALPHA_SC = 0.17677669529663687f;   // hd^-0.5
    const uint32_t* kbh = kbs[h];
    const uint4* kb4 = (const uint4*)kbh;
    // pass 1: integer max score (b128 LDS reads, ascending k within each quad)
    int smax = 0;
#pragma unroll 8
    for (int k4 = 0; k4 < 128; ++k4) {
        uint4 w4 = kb4[k4];
        smax = max(smax, __popc(qw & w4.x));
        smax = max(smax, __popc(qw & w4.y));
        smax = max(smax, __popc(qw & w4.z));
        smax = max(smax, __popc(qw & w4.w));
    }
    float am = __fmul_rn((float)smax, ALPHA_SC);
    // pass 2: Z (ascending k, identical fp expression sequence)
    float Z = 0.0f;
#pragma unroll 4
    for (int k4 = 0; k4 < 128; ++k4) {
        uint4 w4 = kb4[k4];
        Z += expf(__fsub_rn(__fmul_rn((float)__popc(qw & w4.x), ALPHA_SC), am));
        Z += expf(__fsub_rn(__fmul_rn((float)__popc(qw & w4.y), ALPHA_SC), am));
        Z += expf(__fsub_rn(__fmul_rn((float)__popc(qw & w4.z), ALPHA_SC), am));
        Z += expf(__fsub_rn(__fmul_rn((float)__popc(qw & w4.w), ALPHA_SC), am));
    }
    // per-thread P table (33 distinct values); own column only -> no barrier needed
    for (int s = 0; s <= 32; ++s)
        ptab[s][tid] = expf(__fsub_rn(__fmul_rn((float)s, ALPHA_SC), am)) / Z;

    // pass 3: PV, 16 dims per thread, 4-deep ring prefetch of V rows + P values.
    const float* vbase = spk + (size_t)lbase * C3 + 512 + hp * 64 + h * 32 + dh * 16;
    float acc[16];
#pragma unroll
    for (int d = 0; d < 16; ++d) acc[d] = 0.0f;

#pragma unroll
    for (int w = 0; w < 4; ++w) {
        int sw = (w == 0) ? s0r : (w == 1) ? s1r : (w == 2) ? s2r : s3r;
        const float* p = vbase + (size_t)sw * (WIN * C3);
        const uint32_t* kw = kbh + w * 128;

        float4 Vr[4][4];
        float  Pr[4];
#pragma unroll
        for (int j = 0; j < 4; ++j) {
            const float4* pj = (const float4*)(p + (size_t)j * C3);
#pragma unroll
            for (int u = 0; u < 4; ++u) Vr[j][u] = pj[u];
            Pr[j] = ptab[__popc(qw & kw[j])][tid];
        }
        for (int r = 0; r < 128; r += 4) {
#pragma unroll
            for (int j = 0; j < 4; ++j) {
                float P = Pr[j];
                float4 v0 = Vr[j][0], v1 = Vr[j][1], v2 = Vr[j][2], v3 = Vr[j][3];
                // issue prefetch of row r+4+j into slot j (wrap values unused)
                int rn = (r + 4 + j) & 127;
                const float4* pn = (const float4*)(p + (size_t)rn * C3);
#pragma unroll
                for (int u = 0; u < 4; ++u) Vr[j][u] = pn[u];
                Pr[j] = ptab[__popc(qw & kw[rn])][tid];
                // FMA row r+j (ascending k order preserved)
                acc[ 0] = fmaf(P, v0.x, acc[ 0]);
                acc[ 1] = fmaf(P, v0.y, acc[ 1]);
                acc[ 2] = fmaf(P, v0.z, acc[ 2]);
                acc[ 3] = fmaf(P, v0.w, acc[ 3]);
                acc[ 4] = fmaf(P, v1.x, acc[ 4]);
                acc[ 5] = fmaf(P, v1.y, acc[ 5]);
                acc[ 6] = fmaf(P, v1.z, acc[ 6]);
                acc[ 7] = fmaf(P, v1.w, acc[ 7]);
                acc[ 8] = fmaf(P, v2.x, acc[ 8]);
                acc[ 9] = fmaf(P, v2.y, acc[ 9]);
                acc[10] = fmaf(P, v2.z, acc[10]);
                acc[11] = fmaf(P, v2.w, acc[11]);
                acc[12] = fmaf(P, v3.x, acc[12]);
                acc[13] = fmaf(P, v3.y, acc[13]);
                acc[14] = fmaf(P, v3.z, acc[14]);
                acc[15] = fmaf(P, v3.w, acc[15]);
            }
        }
    }

    size_t obase = (size_t)(lbase + n * WIN + q) * CC + (hp * 2 + h) * 32 + dh * 16;
#pragma unroll
    for (int d = 0; d < 16; ++d) out[obase + d] = acc[d];
}

// ---------------------------------------------------------------------------
extern "C" void kernel_launch(void* const* d_in, const int* in_sizes, int n_in,
                              void* d_out, int out_size, void* d_ws, size_t ws_size,
                              hipStream_t stream) {
    const float* x      = (const float*)d_in[0];
    const float* w_qkv  = (const float*)d_in[1];
    const float* b_qkv  = (const float*)d_in[2];
    const float* w_proj = (const float*)d_in[3];
    const float* b_proj = (const float*)d_in[4];
    float* ws = (float*)d_ws;

    float* qkv      = ws;                 // 12582912 floats [T,B,L,3C] (spikes after LIF)
    float* attn_out = ws + 12582912;      // 4194304 floats [T,B,L,C]
    float* proj     = ws + 16777216;      // 4194304 floats [T,B,L,C]
    uint32_t* pkb   = (uint32_t*)proj;    // 262144 u32: aliases proj (dead before gemm_proj)
    float* region   = ws + 20971520;      // 8192 floats
    int*   idxp     = (int*)(ws + 20979712);  // 128 ints
    float* outp     = (float*)d_out;

    region_kernel<<<dim3(BB * NWIN), dim3(256), 0, stream>>>(x, region);
    route_kernel<<<dim3(BB), dim3(64), 0, stream>>>(region, idxp);
    gemm_bias<<<dim3(128, 12), dim3(256), 0, stream>>>(x, w_qkv, b_qkv, qkv,
                                                       TT * BB * LL, C3, CC);
    lif_kernel<<<dim3(3072), dim3(256), 0, stream>>>(qkv, qkv, (size_t)BB * LL * C3);
    pack_kernel<<<dim3(32768), dim3(256), 0, stream>>>(qkv, pkb);
    attn_kernel<<<dim3(TT * BB * NWIN * 4 * 2), dim3(256), 0, stream>>>(qkv, pkb, idxp, attn_out);
    gemm_bias<<<dim3(128, 4), dim3(256), 0, stream>>>(attn_out, w_proj, b_proj, proj,
                                                      TT * BB * LL, CC, CC);
    lif_kernel<<<dim3(1024), dim3(256), 0, stream>>>(proj, outp, (size_t)BB * LL * CC);
}

// Round 7
// 441.144 us; speedup vs baseline: 1.2910x; 1.2910x over previous
//
#include <hip/hip_runtime.h>
#include <cstdint>
#include <cstddef>

#define TT 4
#define BB 4
#define LL 1024
#define CC 256
#define HH 8
#define HD 32
#define NWIN 8
#define WIN 128
#define TOPKN 4
#define C3 768

// ---------------------------------------------------------------------------
// 1. region sums: region[b,n,c] = sum_t sum_r x[t,b,n*128+r,c]
__global__ __launch_bounds__(256) void region_kernel(const float* __restrict__ x,
                                                     float* __restrict__ region) {
    int bn = blockIdx.x;          // b*NWIN + n
    int b = bn >> 3, n = bn & 7;
    int c = threadIdx.x;
    float tot = 0.0f;
    for (int r = 0; r < WIN; ++r) {
        int l = n * WIN + r;
        float s = 0.0f;
        for (int t = 0; t < TT; ++t) {
            s += x[(((size_t)t * BB + b) * LL + l) * CC + c];
        }
        tot += s;
    }
    region[(size_t)bn * CC + c] = tot;
}

// ---------------------------------------------------------------------------
// 2. routing: attn_r[n,m] = dot(region[b,n], region[b,m]) * C^-0.5, top-4 per n
__global__ __launch_bounds__(64) void route_kernel(const float* __restrict__ region,
                                                   int* __restrict__ idx) {
    int b = blockIdx.x;
    __shared__ float reg[NWIN][CC];
    __shared__ float attn_r[NWIN][NWIN];
    int tid = threadIdx.x;
    for (int e = tid; e < NWIN * CC; e += 64)
        reg[e >> 8][e & 255] = region[(size_t)b * NWIN * CC + e];
    __syncthreads();
    int n = tid >> 3, m = tid & 7;
    float s = 0.0f;
    for (int c = 0; c < CC; ++c) s += reg[n][c] * reg[m][c];
    attn_r[n][m] = s * 0.0625f;   // C^-0.5 = 1/16 exact
    __syncthreads();
    if (tid < NWIN) {
        float vals[NWIN];
        for (int m2 = 0; m2 < NWIN; ++m2) vals[m2] = attn_r[tid][m2];
        for (int kk = 0; kk < TOPKN; ++kk) {
            int bi = 0; float bv = vals[0];
            for (int m2 = 1; m2 < NWIN; ++m2) {
                if (vals[m2] > bv) { bv = vals[m2]; bi = m2; }
            }
            idx[(b * NWIN + tid) * TOPKN + kk] = bi;
            vals[bi] = -INFINITY;
        }
    }
}

// ---------------------------------------------------------------------------
// 3. fp32 GEMM + bias (K ascending, exact)
__global__ __launch_bounds__(256) void gemm_bias(const float* __restrict__ A,
                                                 const float* __restrict__ W,
                                                 const float* __restrict__ bias,
                                                 float* __restrict__ C,
                                                 int M, int N, int K) {
    const int BM = 128, BN = 64, BK = 16, TM = 8, TN = 4;
    __shared__ float As[BK][BM + 4];
    __shared__ float Bs[BK][BN];
    int tid = threadIdx.x;
    int tx = tid & 15, ty = tid >> 4;
    int bm = blockIdx.x * BM, bn = blockIdx.y * BN;
    float acc[TM][TN] = {};
    for (int k0 = 0; k0 < K; k0 += BK) {
#pragma unroll
        for (int it = 0; it < 2; ++it) {
            int i = it * 256 + tid;
            int row = i >> 2, kc = (i & 3) * 4;
            float4 v = *(const float4*)(A + (size_t)(bm + row) * K + k0 + kc);
            As[kc + 0][row] = v.x; As[kc + 1][row] = v.y;
            As[kc + 2][row] = v.z; As[kc + 3][row] = v.w;
        }
        {
            int kr = tid >> 4, nc = (tid & 15) * 4;
            float4 v = *(const float4*)(W + (size_t)(k0 + kr) * N + bn + nc);
            *(float4*)&Bs[kr][nc] = v;
        }
        __syncthreads();
#pragma unroll
        for (int kk = 0; kk < BK; ++kk) {
            float a[TM], bb[TN];
            const float4* ap = (const float4*)&As[kk][ty * TM];
            float4 a0 = ap[0], a1 = ap[1];
            a[0]=a0.x; a[1]=a0.y; a[2]=a0.z; a[3]=a0.w;
            a[4]=a1.x; a[5]=a1.y; a[6]=a1.z; a[7]=a1.w;
            float4 b0 = *(const float4*)&Bs[kk][tx * TN];
            bb[0]=b0.x; bb[1]=b0.y; bb[2]=b0.z; bb[3]=b0.w;
#pragma unroll
            for (int i = 0; i < TM; ++i)
#pragma unroll
                for (int j = 0; j < TN; ++j)
                    acc[i][j] = fmaf(a[i], bb[j], acc[i][j]);
        }
        __syncthreads();
    }
#pragma unroll
    for (int i = 0; i < TM; ++i) {
        int row = bm + ty * TM + i;
#pragma unroll
        for (int j = 0; j < TN; ++j) {
            int col = bn + tx * TN + j;
            C[(size_t)row * N + col] = acc[i][j] + bias[col];
        }
    }
}

// ---------------------------------------------------------------------------
// 4. LIF over T
__global__ __launch_bounds__(256) void lif_kernel(const float* src, float* dst, size_t stride) {
    size_t i = ((size_t)blockIdx.x * blockDim.x + threadIdx.x) * 4;
    float v[4] = {0.f, 0.f, 0.f, 0.f};
    for (int t = 0; t < TT; ++t) {
        float4 xv4 = *(const float4*)(src + (size_t)t * stride + i);
        float xv[4] = {xv4.x, xv4.y, xv4.z, xv4.w};
        float sp[4];
#pragma unroll
        for (int j = 0; j < 4; ++j) {
            v[j] = v[j] + (xv[j] - v[j]) * 0.5f;
            bool fire = (v[j] >= 1.0f);
            sp[j] = fire ? 1.0f : 0.0f;
            v[j] = fire ? 0.0f : v[j];
        }
        *(float4*)(dst + (size_t)t * stride + i) = make_float4(sp[0], sp[1], sp[2], sp[3]);
    }
}

// ---------------------------------------------------------------------------
// 4b. pack Q/K spike bits: pk[row][0..7] = q words, pk[row][8..15] = k words
__global__ __launch_bounds__(256) void pack_kernel(const float* __restrict__ spk,
                                                   uint32_t* __restrict__ pk) {
    size_t g = (size_t)blockIdx.x * 256 + threadIdx.x;   // over 16384*512
    int row = (int)(g >> 9);
    int col = (int)(g & 511);
    float v = spk[(size_t)row * C3 + col];
    unsigned long long m = __ballot(v >= 0.5f);
    int lane = threadIdx.x & 63;
    if ((lane & 31) == 0)
        pk[(size_t)row * 16 + (col >> 5)] = (lane < 32) ? (uint32_t)m : (uint32_t)(m >> 32);
}

// ---------------------------------------------------------------------------
// 5a. softmax stats: am = fl(smax*alpha), Z = sum_k exp(fl(s*alpha)-am) ascending k.
//     Block = (t,b,n,hp), 256 threads = (q, h). One output per (t,b,l,head).
__global__ __launch_bounds__(256) void attn_sm(const uint32_t* __restrict__ pk,
                                               const int* __restrict__ idxws,
                                               float2* __restrict__ amz) {
    int bid = blockIdx.x;
    int hp = bid & 3, n = (bid >> 2) & 7, b = (bid >> 5) & 3, t = bid >> 7;
    __shared__ uint32_t kbs[2][512];
    int tid = threadIdx.x;
    int q = tid & 127, h = tid >> 7;
    int lbase = (t * BB + b) * LL;

    const int* ip = idxws + (b * NWIN + n) * TOPKN;
    int s0r = ip[0], s1r = ip[1], s2r = ip[2], s3r = ip[3];

#pragma unroll 4
    for (int e = tid; e < 1024; e += 256) {
        int hh = e >> 9, kk = e & 511;
        int w = kk >> 7;
        int sw = (w == 0) ? s0r : (w == 1) ? s1r : (w == 2) ? s2r : s3r;
        int row = sw * WIN + (kk & 127);
        kbs[hh][kk] = pk[(size_t)(lbase + row) * 16 + 8 + hp * 2 + hh];
    }
    uint32_t qw = pk[(size_t)(lbase + n * WIN + q) * 16 + hp * 2 + h];
    __syncthreads();

    const float ALPHA_SC = 0.17677669529663687f;   // hd^-0.5
    const uint4* kb4 = (const uint4*)kbs[h];
    int smax = 0;
#pragma unroll 8
    for (int k4 = 0; k4 < 128; ++k4) {
        uint4 w4 = kb4[k4];
        smax = max(smax, __popc(qw & w4.x));
        smax = max(smax, __popc(qw & w4.y));
        smax = max(smax, __popc(qw & w4.z));
        smax = max(smax, __popc(qw & w4.w));
    }
    float am = __fmul_rn((float)smax, ALPHA_SC);
    float Z = 0.0f;
#pragma unroll 4
    for (int k4 = 0; k4 < 128; ++k4) {
        uint4 w4 = kb4[k4];
        Z += expf(__fsub_rn(__fmul_rn((float)__popc(qw & w4.x), ALPHA_SC), am));
        Z += expf(__fsub_rn(__fmul_rn((float)__popc(qw & w4.y), ALPHA_SC), am));
        Z += expf(__fsub_rn(__fmul_rn((float)__popc(qw & w4.z), ALPHA_SC), am));
        Z += expf(__fsub_rn(__fmul_rn((float)__popc(qw & w4.w), ALPHA_SC), am));
    }
    amz[(size_t)(lbase + n * WIN + q) * HH + hp * 2 + h] = make_float2(am, Z);
}

// ---------------------------------------------------------------------------
// 5b. PV: Block = (t,b,n,hp,dh), 256 threads = (q,h), 16 d-dims per thread.
//     P-table from (am,Z) (bitwise-identical exprs); 2-deep V/P ring (r4-proven).
__global__ __launch_bounds__(256, 4) void attn_pv(const float* __restrict__ spk,
                                                  const uint32_t* __restrict__ pk,
                                                  const int* __restrict__ idxws,
                                                  const float2* __restrict__ amz,
                                                  float* __restrict__ out) {
    int bid = blockIdx.x;
    int dh = bid & 1, hp = (bid >> 1) & 3, n = (bid >> 3) & 7, b = (bid >> 6) & 3, t = bid >> 8;
    __shared__ uint32_t kbs[2][512];
    __shared__ float ptab[33][256];
    int tid = threadIdx.x;
    int q = tid & 127, h = tid >> 7;
    int lbase = (t * BB + b) * LL;

    const int* ip = idxws + (b * NWIN + n) * TOPKN;
    int s0r = ip[0], s1r = ip[1], s2r = ip[2], s3r = ip[3];

#pragma unroll 4
    for (int e = tid; e < 1024; e += 256) {
        int hh = e >> 9, kk = e & 511;
        int w = kk >> 7;
        int sw = (w == 0) ? s0r : (w == 1) ? s1r : (w == 2) ? s2r : s3r;
        int row = sw * WIN + (kk & 127);
        kbs[hh][kk] = pk[(size_t)(lbase + row) * 16 + 8 + hp * 2 + hh];
    }
    uint32_t qw = pk[(size_t)(lbase + n * WIN + q) * 16 + hp * 2 + h];

    float2 az = amz[(size_t)(lbase + n * WIN + q) * HH + hp * 2 + h];
    const float ALPHA_SC = 0.17677669529663687f;   // hd^-0.5
    // per-thread P table; own column only -> no barrier needed for ptab
    for (int s = 0; s <= 32; ++s)
        ptab[s][tid] = expf(__fsub_rn(__fmul_rn((float)s, ALPHA_SC), az.x)) / az.y;
    __syncthreads();   // kbs ready

    const uint32_t* kbh = kbs[h];
    const float* vbase = spk + (size_t)lbase * C3 + 512 + hp * 64 + h * 32 + dh * 16;
    float acc[16];
#pragma unroll
    for (int d = 0; d < 16; ++d) acc[d] = 0.0f;

#pragma unroll
    for (int w = 0; w < 4; ++w) {
        int sw = (w == 0) ? s0r : (w == 1) ? s1r : (w == 2) ? s2r : s3r;
        const float* p = vbase + (size_t)sw * (WIN * C3);
        const uint32_t* kw = kbh + w * 128;

        // rolling row pointers: pA = even rows, pB = odd rows (no wrap-mul;
        // tail prefetches read past the window into valid ws memory, unused)
        const float* pA = p;
        const float* pB = p + C3;
        float4 Av[4], Bv[4];
#pragma unroll
        for (int j = 0; j < 4; ++j) Av[j] = ((const float4*)pA)[j];
#pragma unroll
        for (int j = 0; j < 4; ++j) Bv[j] = ((const float4*)pB)[j];
        float Pa = ptab[__popc(qw & kw[0])][tid];
        float Pb = ptab[__popc(qw & kw[1])][tid];

        for (int r = 0; r < 128; r += 2) {
            // consume row r (A)
            {
                float P = Pa;
                float4 v0 = Av[0], v1 = Av[1], v2 = Av[2], v3 = Av[3];
                pA += 2 * C3;
                const float4* pn = (const float4*)pA;
#pragma unroll
                for (int u = 0; u < 4; ++u) Av[u] = pn[u];
                Pa = ptab[__popc(qw & kw[(r + 2) & 511])][tid];  // r+2<=128: in-LDS, tail unused
                acc[ 0] = fmaf(P, v0.x, acc[ 0]);
                acc[ 1] = fmaf(P, v0.y, acc[ 1]);
                acc[ 2] = fmaf(P, v0.z, acc[ 2]);
                acc[ 3] = fmaf(P, v0.w, acc[ 3]);
                acc[ 4] = fmaf(P, v1.x, acc[ 4]);
                acc[ 5] = fmaf(P, v1.y, acc[ 5]);
                acc[ 6] = fmaf(P, v1.z, acc[ 6]);
                acc[ 7] = fmaf(P, v1.w, acc[ 7]);
                acc[ 8] = fmaf(P, v2.x, acc[ 8]);
                acc[ 9] = fmaf(P, v2.y, acc[ 9]);
                acc[10] = fmaf(P, v2.z, acc[10]);
                acc[11] = fmaf(P, v2.w, acc[11]);
                acc[12] = fmaf(P, v3.x, acc[12]);
                acc[13] = fmaf(P, v3.y, acc[13]);
                acc[14] = fmaf(P, v3.z, acc[14]);
                acc[15] = fmaf(P, v3.w, acc[15]);
            }
            // consume row r+1 (B)
            {
                float P = Pb;
                float4 v0 = Bv[0], v1 = Bv[1], v2 = Bv[2], v3 = Bv[3];
                pB += 2 * C3;
                const float4* pn = (const float4*)pB;
#pragma unroll
                for (int u = 0; u < 4; ++u) Bv[u] = pn[u];
                Pb = ptab[__popc(qw & kw[(r + 3) & 511])][tid];
                acc[ 0] = fmaf(P, v0.x, acc[ 0]);
                acc[ 1] = fmaf(P, v0.y, acc[ 1]);
                acc[ 2] = fmaf(P, v0.z, acc[ 2]);
                acc[ 3] = fmaf(P, v0.w, acc[ 3]);
                acc[ 4] = fmaf(P, v1.x, acc[ 4]);
                acc[ 5] = fmaf(P, v1.y, acc[ 5]);
                acc[ 6] = fmaf(P, v1.z, acc[ 6]);
                acc[ 7] = fmaf(P, v1.w, acc[ 7]);
                acc[ 8] = fmaf(P, v2.x, acc[ 8]);
                acc[ 9] = fmaf(P, v2.y, acc[ 9]);
                acc[10] = fmaf(P, v2.z, acc[10]);
                acc[11] = fmaf(P, v2.w, acc[11]);
                acc[12] = fmaf(P, v3.x, acc[12]);
                acc[13] = fmaf(P, v3.y, acc[13]);
                acc[14] = fmaf(P, v3.z, acc[14]);
                acc[15] = fmaf(P, v3.w, acc[15]);
            }
        }
    }

    size_t obase = (size_t)(lbase + n * WIN + q) * CC + (hp * 2 + h) * 32 + dh * 16;
#pragma unroll
    for (int d = 0; d < 16; ++d) out[obase + d] = acc[d];
}

// ---------------------------------------------------------------------------
extern "C" void kernel_launch(void* const* d_in, const int* in_sizes, int n_in,
                              void* d_out, int out_size, void* d_ws, size_t ws_size,
                              hipStream_t stream) {
    const float* x      = (const float*)d_in[0];
    const float* w_qkv  = (const float*)d_in[1];
    const float* b_qkv  = (const float*)d_in[2];
    const float* w_proj = (const float*)d_in[3];
    const float* b_proj = (const float*)d_in[4];
    float* ws = (float*)d_ws;

    float* qkv      = ws;                 // 12582912 floats [T,B,L,3C] (spikes after LIF)
    float* attn_out = ws + 12582912;      // 4194304 floats [T,B,L,C]
    float* proj     = ws + 16777216;      // 4194304 floats [T,B,L,C]
    uint32_t* pkb   = (uint32_t*)proj;    // 262144 u32: aliases proj (dead before gemm_proj)
    float* region   = ws + 20971520;      // 8192 floats
    int*   idxp     = (int*)(ws + 20979712);  // 128 ints
    float2* amzp    = (float2*)(ws + 20979840); // 131072 float2 [T,B,L,H]
    float* outp     = (float*)d_out;

    region_kernel<<<dim3(BB * NWIN), dim3(256), 0, stream>>>(x, region);
    route_kernel<<<dim3(BB), dim3(64), 0, stream>>>(region, idxp);
    gemm_bias<<<dim3(128, 12), dim3(256), 0, stream>>>(x, w_qkv, b_qkv, qkv,
                                                       TT * BB * LL, C3, CC);
    lif_kernel<<<dim3(3072), dim3(256), 0, stream>>>(qkv, qkv, (size_t)BB * LL * C3);
    pack_kernel<<<dim3(32768), dim3(256), 0, stream>>>(qkv, pkb);
    attn_sm<<<dim3(TT * BB * NWIN * 4), dim3(256), 0, stream>>>(pkb, idxp, amzp);
    attn_pv<<<dim3(TT * BB * NWIN * 4 * 2), dim3(256), 0, stream>>>(qkv, pkb, idxp, amzp, attn_out);
    gemm_bias<<<dim3(128, 4), dim3(256), 0, stream>>>(attn_out, w_proj, b_proj, proj,
                                                      TT * BB * LL, CC, CC);
    lif_kernel<<<dim3(1024), dim3(256), 0, stream>>>(proj, outp, (size_t)BB * LL * CC);
}

// Round 8
// 369.637 us; speedup vs baseline: 1.5407x; 1.1935x over previous
//
#include <hip/hip_runtime.h>
#include <cstdint>
#include <cstddef>

#define TT 4
#define BB 4
#define LL 1024
#define CC 256
#define HH 8
#define HD 32
#define NWIN 8
#define WIN 128
#define TOPKN 4
#define C3 768

// ---------------------------------------------------------------------------
// 1. region sums
__global__ __launch_bounds__(256) void region_kernel(const float* __restrict__ x,
                                                     float* __restrict__ region) {
    int bn = blockIdx.x;          // b*NWIN + n
    int b = bn >> 3, n = bn & 7;
    int c = threadIdx.x;
    float tot = 0.0f;
    for (int r = 0; r < WIN; ++r) {
        int l = n * WIN + r;
        float s = 0.0f;
        for (int t = 0; t < TT; ++t) {
            s += x[(((size_t)t * BB + b) * LL + l) * CC + c];
        }
        tot += s;
    }
    region[(size_t)bn * CC + c] = tot;
}

// ---------------------------------------------------------------------------
// 2. routing
__global__ __launch_bounds__(64) void route_kernel(const float* __restrict__ region,
                                                   int* __restrict__ idx) {
    int b = blockIdx.x;
    __shared__ float reg[NWIN][CC];
    __shared__ float attn_r[NWIN][NWIN];
    int tid = threadIdx.x;
    for (int e = tid; e < NWIN * CC; e += 64)
        reg[e >> 8][e & 255] = region[(size_t)b * NWIN * CC + e];
    __syncthreads();
    int n = tid >> 3, m = tid & 7;
    float s = 0.0f;
    for (int c = 0; c < CC; ++c) s += reg[n][c] * reg[m][c];
    attn_r[n][m] = s * 0.0625f;   // C^-0.5 = 1/16 exact
    __syncthreads();
    if (tid < NWIN) {
        float vals[NWIN];
        for (int m2 = 0; m2 < NWIN; ++m2) vals[m2] = attn_r[tid][m2];
        for (int kk = 0; kk < TOPKN; ++kk) {
            int bi = 0; float bv = vals[0];
            for (int m2 = 1; m2 < NWIN; ++m2) {
                if (vals[m2] > bv) { bv = vals[m2]; bi = m2; }
            }
            idx[(b * NWIN + tid) * TOPKN + kk] = bi;
            vals[bi] = -INFINITY;
        }
    }
}

// ---------------------------------------------------------------------------
// 3. fp32 GEMM + bias (K ascending, exact)
__global__ __launch_bounds__(256) void gemm_bias(const float* __restrict__ A,
                                                 const float* __restrict__ W,
                                                 const float* __restrict__ bias,
                                                 float* __restrict__ C,
                                                 int M, int N, int K) {
    const int BM = 128, BN = 64, BK = 16, TM = 8, TN = 4;
    __shared__ float As[BK][BM + 4];
    __shared__ float Bs[BK][BN];
    int tid = threadIdx.x;
    int tx = tid & 15, ty = tid >> 4;
    int bm = blockIdx.x * BM, bn = blockIdx.y * BN;
    float acc[TM][TN] = {};
    for (int k0 = 0; k0 < K; k0 += BK) {
#pragma unroll
        for (int it = 0; it < 2; ++it) {
            int i = it * 256 + tid;
            int row = i >> 2, kc = (i & 3) * 4;
            float4 v = *(const float4*)(A + (size_t)(bm + row) * K + k0 + kc);
            As[kc + 0][row] = v.x; As[kc + 1][row] = v.y;
            As[kc + 2][row] = v.z; As[kc + 3][row] = v.w;
        }
        {
            int kr = tid >> 4, nc = (tid & 15) * 4;
            float4 v = *(const float4*)(W + (size_t)(k0 + kr) * N + bn + nc);
            *(float4*)&Bs[kr][nc] = v;
        }
        __syncthreads();
#pragma unroll
        for (int kk = 0; kk < BK; ++kk) {
            float a[TM], bb[TN];
            const float4* ap = (const float4*)&As[kk][ty * TM];
            float4 a0 = ap[0], a1 = ap[1];
            a[0]=a0.x; a[1]=a0.y; a[2]=a0.z; a[3]=a0.w;
            a[4]=a1.x; a[5]=a1.y; a[6]=a1.z; a[7]=a1.w;
            float4 b0 = *(const float4*)&Bs[kk][tx * TN];
            bb[0]=b0.x; bb[1]=b0.y; bb[2]=b0.z; bb[3]=b0.w;
#pragma unroll
            for (int i = 0; i < TM; ++i)
#pragma unroll
                for (int j = 0; j < TN; ++j)
                    acc[i][j] = fmaf(a[i], bb[j], acc[i][j]);
        }
        __syncthreads();
    }
#pragma unroll
    for (int i = 0; i < TM; ++i) {
        int row = bm + ty * TM + i;
#pragma unroll
        for (int j = 0; j < TN; ++j) {
            int col = bn + tx * TN + j;
            C[(size_t)row * N + col] = acc[i][j] + bias[col];
        }
    }
}

// ---------------------------------------------------------------------------
// 4. LIF over T
__global__ __launch_bounds__(256) void lif_kernel(const float* src, float* dst, size_t stride) {
    size_t i = ((size_t)blockIdx.x * blockDim.x + threadIdx.x) * 4;
    float v[4] = {0.f, 0.f, 0.f, 0.f};
    for (int t = 0; t < TT; ++t) {
        float4 xv4 = *(const float4*)(src + (size_t)t * stride + i);
        float xv[4] = {xv4.x, xv4.y, xv4.z, xv4.w};
        float sp[4];
#pragma unroll
        for (int j = 0; j < 4; ++j) {
            v[j] = v[j] + (xv[j] - v[j]) * 0.5f;
            bool fire = (v[j] >= 1.0f);
            sp[j] = fire ? 1.0f : 0.0f;
            v[j] = fire ? 0.0f : v[j];
        }
        *(float4*)(dst + (size_t)t * stride + i) = make_float4(sp[0], sp[1], sp[2], sp[3]);
    }
}

// ---------------------------------------------------------------------------
// 4b. pack Q/K spike bits
__global__ __launch_bounds__(256) void pack_kernel(const float* __restrict__ spk,
                                                   uint32_t* __restrict__ pk) {
    size_t g = (size_t)blockIdx.x * 256 + threadIdx.x;   // over 16384*512
    int row = (int)(g >> 9);
    int col = (int)(g & 511);
    float v = spk[(size_t)row * C3 + col];
    unsigned long long m = __ballot(v >= 0.5f);
    int lane = threadIdx.x & 63;
    if ((lane & 31) == 0)
        pk[(size_t)row * 16 + (col >> 5)] = (lane < 32) ? (uint32_t)m : (uint32_t)(m >> 32);
}

// ---------------------------------------------------------------------------
// 5a. softmax stats (unchanged from r7): am, Z per (t,b,l,head)
__global__ __launch_bounds__(256) void attn_sm(const uint32_t* __restrict__ pk,
                                               const int* __restrict__ idxws,
                                               float2* __restrict__ amz) {
    int bid = blockIdx.x;
    int hp = bid & 3, n = (bid >> 2) & 7, b = (bid >> 5) & 3, t = bid >> 7;
    __shared__ uint32_t kbs[2][512];
    int tid = threadIdx.x;
    int q = tid & 127, h = tid >> 7;
    int lbase = (t * BB + b) * LL;

    const int* ip = idxws + (b * NWIN + n) * TOPKN;
    int s0r = ip[0], s1r = ip[1], s2r = ip[2], s3r = ip[3];

#pragma unroll 4
    for (int e = tid; e < 1024; e += 256) {
        int hh = e >> 9, kk = e & 511;
        int w = kk >> 7;
        int sw = (w == 0) ? s0r : (w == 1) ? s1r : (w == 2) ? s2r : s3r;
        int row = sw * WIN + (kk & 127);
        kbs[hh][kk] = pk[(size_t)(lbase + row) * 16 + 8 + hp * 2 + hh];
    }
    uint32_t qw = pk[(size_t)(lbase + n * WIN + q) * 16 + hp * 2 + h];
    __syncthreads();

    const float ALPHA_SC = 0.17677669529663687f;   // hd^-0.5
    const uint4* kb4 = (const uint4*)kbs[h];
    int smax = 0;
#pragma unroll 8
    for (int k4 = 0; k4 < 128; ++k4) {
        uint4 w4 = kb4[k4];
        smax = max(smax, __popc(qw & w4.x));
        smax = max(smax, __popc(qw & w4.y));
        smax = max(smax, __popc(qw & w4.z));
        smax = max(smax, __popc(qw & w4.w));
    }
    float am = __fmul_rn((float)smax, ALPHA_SC);
    float Z = 0.0f;
#pragma unroll 4
    for (int k4 = 0; k4 < 128; ++k4) {
        uint4 w4 = kb4[k4];
        Z += expf(__fsub_rn(__fmul_rn((float)__popc(qw & w4.x), ALPHA_SC), am));
        Z += expf(__fsub_rn(__fmul_rn((float)__popc(qw & w4.y), ALPHA_SC), am));
        Z += expf(__fsub_rn(__fmul_rn((float)__popc(qw & w4.z), ALPHA_SC), am));
        Z += expf(__fsub_rn(__fmul_rn((float)__popc(qw & w4.w), ALPHA_SC), am));
    }
    amz[(size_t)(lbase + n * WIN + q) * HH + hp * 2 + h] = make_float2(am, Z);
}

// ---------------------------------------------------------------------------
// 5b. PV v8: Block = (t,b,n,hp,h): 1024 blocks, 256 threads = (q 0..127, dh 0..1).
//     V double-buffered window staging in LDS (issue-early loads, write-late).
//     Inner loop: LDS-only reads (wave-uniform broadcast) + 16 fma/row.
__global__ __launch_bounds__(256, 3) void attn_pv(const float* __restrict__ spk,
                                                  const uint32_t* __restrict__ pk,
                                                  const int* __restrict__ idxws,
                                                  const float2* __restrict__ amz,
                                                  float* __restrict__ out) {
    int bid = blockIdx.x;
    int h = bid & 1, hp = (bid >> 1) & 3, n = (bid >> 3) & 7, b = (bid >> 6) & 3, t = bid >> 8;
    __shared__ float   Vlds[2][WIN][32];     // 32 KB: [buf][row][32 floats of this (hp,h)]
    __shared__ float   ptab[33][WIN];        // 16.9 KB
    __shared__ uint32_t kbs[4 * WIN];        // 2 KB (this h only)
    int tid = threadIdx.x;
    int q = tid & 127, dh = tid >> 7;
    int lbase = (t * BB + b) * LL;

    const int* ip = idxws + (b * NWIN + n) * TOPKN;
    int s0r = ip[0], s1r = ip[1], s2r = ip[2], s3r = ip[3];

    // stage gathered K bit-words (this h)
#pragma unroll 2
    for (int e = tid; e < 512; e += 256) {
        int w = e >> 7;
        int sw = (w == 0) ? s0r : (w == 1) ? s1r : (w == 2) ? s2r : s3r;
        int row = sw * WIN + (e & 127);
        kbs[e] = pk[(size_t)(lbase + row) * 16 + 8 + hp * 2 + h];
    }
    uint32_t qw = pk[(size_t)(lbase + n * WIN + q) * 16 + hp * 2 + h];

    // P table: one column per q (dh==0 threads write; dh==1 shares)
    float2 az = amz[(size_t)(lbase + n * WIN + q) * HH + hp * 2 + h];
    const float ALPHA_SC = 0.17677669529663687f;   // hd^-0.5
    if (tid < 128) {
        for (int s = 0; s <= 32; ++s)
            ptab[s][tid] = expf(__fsub_rn(__fmul_rn((float)s, ALPHA_SC), az.x)) / az.y;
    }

    // V window source base (this block's 32-float slice per row)
    const float* vsrc = spk + (size_t)lbase * C3 + 512 + hp * 64 + h * 32;

    // prologue: stage window 0 into buf 0
    {
        int sw = s0r;
        const float* src = vsrc + (size_t)sw * (WIN * C3);
        float4 st[4];
#pragma unroll
        for (int it = 0; it < 4; ++it) {
            int e = tid + it * 256;
            st[it] = *(const float4*)(src + (size_t)(e >> 3) * C3 + (e & 7) * 4);
        }
#pragma unroll
        for (int it = 0; it < 4; ++it) {
            int e = tid + it * 256;
            *(float4*)&Vlds[0][e >> 3][(e & 7) * 4] = st[it];
        }
    }
    __syncthreads();   // Vlds buf0 + kbs + ptab ready

    float acc[16];
#pragma unroll
    for (int d = 0; d < 16; ++d) acc[d] = 0.0f;

#pragma unroll
    for (int w = 0; w < 4; ++w) {
        // issue next window's loads early (latency hides under compute)
        float4 st[4];
        if (w < 3) {
            int swn = (w == 0) ? s1r : (w == 1) ? s2r : s3r;
            const float* src = vsrc + (size_t)swn * (WIN * C3);
#pragma unroll
            for (int it = 0; it < 4; ++it) {
                int e = tid + it * 256;
                st[it] = *(const float4*)(src + (size_t)(e >> 3) * C3 + (e & 7) * 4);
            }
        }

        // compute window w from Vlds[w&1] (wave-uniform rows; 2-deep reg ring)
        const float* vb = &Vlds[w & 1][0][dh * 16];
        const uint32_t* kw = kbs + w * 128;
        float4 Av[4], Bv[4];
#pragma unroll
        for (int u = 0; u < 4; ++u) Av[u] = ((const float4*)vb)[u];
#pragma unroll
        for (int u = 0; u < 4; ++u) Bv[u] = ((const float4*)(vb + 32))[u];
        float Pa = ptab[__popc(qw & kw[0])][q];
        float Pb = ptab[__popc(qw & kw[1])][q];

        for (int r = 0; r < 128; r += 2) {
            {
                float P = Pa;
                float4 v0 = Av[0], v1 = Av[1], v2 = Av[2], v3 = Av[3];
                const float4* pn = (const float4*)(vb + (size_t)((r + 2) & 127) * 32);
#pragma unroll
                for (int u = 0; u < 4; ++u) Av[u] = pn[u];
                Pa = ptab[__popc(qw & kw[(r + 2) & 127])][q];
                acc[ 0] = fmaf(P, v0.x, acc[ 0]);
                acc[ 1] = fmaf(P, v0.y, acc[ 1]);
                acc[ 2] = fmaf(P, v0.z, acc[ 2]);
                acc[ 3] = fmaf(P, v0.w, acc[ 3]);
                acc[ 4] = fmaf(P, v1.x, acc[ 4]);
                acc[ 5] = fmaf(P, v1.y, acc[ 5]);
                acc[ 6] = fmaf(P, v1.z, acc[ 6]);
                acc[ 7] = fmaf(P, v1.w, acc[ 7]);
                acc[ 8] = fmaf(P, v2.x, acc[ 8]);
                acc[ 9] = fmaf(P, v2.y, acc[ 9]);
                acc[10] = fmaf(P, v2.z, acc[10]);
                acc[11] = fmaf(P, v2.w, acc[11]);
                acc[12] = fmaf(P, v3.x, acc[12]);
                acc[13] = fmaf(P, v3.y, acc[13]);
                acc[14] = fmaf(P, v3.z, acc[14]);
                acc[15] = fmaf(P, v3.w, acc[15]);
            }
            {
                float P = Pb;
                float4 v0 = Bv[0], v1 = Bv[1], v2 = Bv[2], v3 = Bv[3];
                const float4* pn = (const float4*)(vb + (size_t)((r + 3) & 127) * 32);
#pragma unroll
                for (int u = 0; u < 4; ++u) Bv[u] = pn[u];
                Pb = ptab[__popc(qw & kw[(r + 3) & 127])][q];
                acc[ 0] = fmaf(P, v0.x, acc[ 0]);
                acc[ 1] = fmaf(P, v0.y, acc[ 1]);
                acc[ 2] = fmaf(P, v0.z, acc[ 2]);
                acc[ 3] = fmaf(P, v0.w, acc[ 3]);
                acc[ 4] = fmaf(P, v1.x, acc[ 4]);
                acc[ 5] = fmaf(P, v1.y, acc[ 5]);
                acc[ 6] = fmaf(P, v1.z, acc[ 6]);
                acc[ 7] = fmaf(P, v1.w, acc[ 7]);
                acc[ 8] = fmaf(P, v2.x, acc[ 8]);
                acc[ 9] = fmaf(P, v2.y, acc[ 9]);
                acc[10] = fmaf(P, v2.z, acc[10]);
                acc[11] = fmaf(P, v2.w, acc[11]);
                acc[12] = fmaf(P, v3.x, acc[12]);
                acc[13] = fmaf(P, v3.y, acc[13]);
                acc[14] = fmaf(P, v3.z, acc[14]);
                acc[15] = fmaf(P, v3.w, acc[15]);
            }
        }

        // write next window into the other buffer, then one barrier
        if (w < 3) {
#pragma unroll
            for (int it = 0; it < 4; ++it) {
                int e = tid + it * 256;
                *(float4*)&Vlds[(w + 1) & 1][e >> 3][(e & 7) * 4] = st[it];
            }
            __syncthreads();
        }
    }

    size_t obase = (size_t)(lbase + n * WIN + q) * CC + (hp * 2 + h) * 32 + dh * 16;
#pragma unroll
    for (int d = 0; d < 16; ++d) out[obase + d] = acc[d];
}

// ---------------------------------------------------------------------------
extern "C" void kernel_launch(void* const* d_in, const int* in_sizes, int n_in,
                              void* d_out, int out_size, void* d_ws, size_t ws_size,
                              hipStream_t stream) {
    const float* x      = (const float*)d_in[0];
    const float* w_qkv  = (const float*)d_in[1];
    const float* b_qkv  = (const float*)d_in[2];
    const float* w_proj = (const float*)d_in[3];
    const float* b_proj = (const float*)d_in[4];
    float* ws = (float*)d_ws;

    float* qkv      = ws;                 // 12582912 floats [T,B,L,3C] (spikes after LIF)
    float* attn_out = ws + 12582912;      // 4194304 floats [T,B,L,C]
    float* proj     = ws + 16777216;      // 4194304 floats [T,B,L,C]
    uint32_t* pkb   = (uint32_t*)proj;    // 262144 u32: aliases proj (dead before gemm_proj)
    float* region   = ws + 20971520;      // 8192 floats
    int*   idxp     = (int*)(ws + 20979712);  // 128 ints
    float2* amzp    = (float2*)(ws + 20979840); // 131072 float2 [T,B,L,H]
    float* outp     = (float*)d_out;

    region_kernel<<<dim3(BB * NWIN), dim3(256), 0, stream>>>(x, region);
    route_kernel<<<dim3(BB), dim3(64), 0, stream>>>(region, idxp);
    gemm_bias<<<dim3(128, 12), dim3(256), 0, stream>>>(x, w_qkv, b_qkv, qkv,
                                                       TT * BB * LL, C3, CC);
    lif_kernel<<<dim3(3072), dim3(256), 0, stream>>>(qkv, qkv, (size_t)BB * LL * C3);
    pack_kernel<<<dim3(32768), dim3(256), 0, stream>>>(qkv, pkb);
    attn_sm<<<dim3(TT * BB * NWIN * 4), dim3(256), 0, stream>>>(pkb, idxp, amzp);
    attn_pv<<<dim3(TT * BB * NWIN * 4 * 2), dim3(256), 0, stream>>>(qkv, pkb, idxp, amzp, attn_out);
    gemm_bias<<<dim3(128, 4), dim3(256), 0, stream>>>(attn_out, w_proj, b_proj, proj,
                                                      TT * BB * LL, CC, CC);
    lif_kernel<<<dim3(1024), dim3(256), 0, stream>>>(proj, outp, (size_t)BB * LL * CC);
}

// Round 9
// 361.871 us; speedup vs baseline: 1.5738x; 1.0215x over previous
//
#include <hip/hip_runtime.h>
#include <cstdint>
#include <cstddef>

#define TT 4
#define BB 4
#define LL 1024
#define CC 256
#define HH 8
#define HD 32
#define NWIN 8
#define WIN 128
#define TOPKN 4
#define C3 768

// ---------------------------------------------------------------------------
// 1. region sums
__global__ __launch_bounds__(256) void region_kernel(const float* __restrict__ x,
                                                     float* __restrict__ region) {
    int bn = blockIdx.x;          // b*NWIN + n
    int b = bn >> 3, n = bn & 7;
    int c = threadIdx.x;
    float tot = 0.0f;
    for (int r = 0; r < WIN; ++r) {
        int l = n * WIN + r;
        float s = 0.0f;
        for (int t = 0; t < TT; ++t) {
            s += x[(((size_t)t * BB + b) * LL + l) * CC + c];
        }
        tot += s;
    }
    region[(size_t)bn * CC + c] = tot;
}

// ---------------------------------------------------------------------------
// 2. routing
__global__ __launch_bounds__(64) void route_kernel(const float* __restrict__ region,
                                                   int* __restrict__ idx) {
    int b = blockIdx.x;
    __shared__ float reg[NWIN][CC];
    __shared__ float attn_r[NWIN][NWIN];
    int tid = threadIdx.x;
    for (int e = tid; e < NWIN * CC; e += 64)
        reg[e >> 8][e & 255] = region[(size_t)b * NWIN * CC + e];
    __syncthreads();
    int n = tid >> 3, m = tid & 7;
    float s = 0.0f;
    for (int c = 0; c < CC; ++c) s += reg[n][c] * reg[m][c];
    attn_r[n][m] = s * 0.0625f;   // C^-0.5 = 1/16 exact
    __syncthreads();
    if (tid < NWIN) {
        float vals[NWIN];
        for (int m2 = 0; m2 < NWIN; ++m2) vals[m2] = attn_r[tid][m2];
        for (int kk = 0; kk < TOPKN; ++kk) {
            int bi = 0; float bv = vals[0];
            for (int m2 = 1; m2 < NWIN; ++m2) {
                if (vals[m2] > bv) { bv = vals[m2]; bi = m2; }
            }
            idx[(b * NWIN + tid) * TOPKN + kk] = bi;
            vals[bi] = -INFINITY;
        }
    }
}

// ---------------------------------------------------------------------------
// 3. fp32 GEMM + bias (K ascending, exact)
__global__ __launch_bounds__(256) void gemm_bias(const float* __restrict__ A,
                                                 const float* __restrict__ W,
                                                 const float* __restrict__ bias,
                                                 float* __restrict__ C,
                                                 int M, int N, int K) {
    const int BM = 128, BN = 64, BK = 16, TM = 8, TN = 4;
    __shared__ float As[BK][BM + 4];
    __shared__ float Bs[BK][BN];
    int tid = threadIdx.x;
    int tx = tid & 15, ty = tid >> 4;
    int bm = blockIdx.x * BM, bn = blockIdx.y * BN;
    float acc[TM][TN] = {};
    for (int k0 = 0; k0 < K; k0 += BK) {
#pragma unroll
        for (int it = 0; it < 2; ++it) {
            int i = it * 256 + tid;
            int row = i >> 2, kc = (i & 3) * 4;
            float4 v = *(const float4*)(A + (size_t)(bm + row) * K + k0 + kc);
            As[kc + 0][row] = v.x; As[kc + 1][row] = v.y;
            As[kc + 2][row] = v.z; As[kc + 3][row] = v.w;
        }
        {
            int kr = tid >> 4, nc = (tid & 15) * 4;
            float4 v = *(const float4*)(W + (size_t)(k0 + kr) * N + bn + nc);
            *(float4*)&Bs[kr][nc] = v;
        }
        __syncthreads();
#pragma unroll
        for (int kk = 0; kk < BK; ++kk) {
            float a[TM], bb[TN];
            const float4* ap = (const float4*)&As[kk][ty * TM];
            float4 a0 = ap[0], a1 = ap[1];
            a[0]=a0.x; a[1]=a0.y; a[2]=a0.z; a[3]=a0.w;
            a[4]=a1.x; a[5]=a1.y; a[6]=a1.z; a[7]=a1.w;
            float4 b0 = *(const float4*)&Bs[kk][tx * TN];
            bb[0]=b0.x; bb[1]=b0.y; bb[2]=b0.z; bb[3]=b0.w;
#pragma unroll
            for (int i = 0; i < TM; ++i)
#pragma unroll
                for (int j = 0; j < TN; ++j)
                    acc[i][j] = fmaf(a[i], bb[j], acc[i][j]);
        }
        __syncthreads();
    }
#pragma unroll
    for (int i = 0; i < TM; ++i) {
        int row = bm + ty * TM + i;
#pragma unroll
        for (int j = 0; j < TN; ++j) {
            int col = bn + tx * TN + j;
            C[(size_t)row * N + col] = acc[i][j] + bias[col];
        }
    }
}

// ---------------------------------------------------------------------------
// 4. LIF over T
__global__ __launch_bounds__(256) void lif_kernel(const float* src, float* dst, size_t stride) {
    size_t i = ((size_t)blockIdx.x * blockDim.x + threadIdx.x) * 4;
    float v[4] = {0.f, 0.f, 0.f, 0.f};
    for (int t = 0; t < TT; ++t) {
        float4 xv4 = *(const float4*)(src + (size_t)t * stride + i);
        float xv[4] = {xv4.x, xv4.y, xv4.z, xv4.w};
        float sp[4];
#pragma unroll
        for (int j = 0; j < 4; ++j) {
            v[j] = v[j] + (xv[j] - v[j]) * 0.5f;
            bool fire = (v[j] >= 1.0f);
            sp[j] = fire ? 1.0f : 0.0f;
            v[j] = fire ? 0.0f : v[j];
        }
        *(float4*)(dst + (size_t)t * stride + i) = make_float4(sp[0], sp[1], sp[2], sp[3]);
    }
}

// ---------------------------------------------------------------------------
// 4b. pack Q/K spike bits
__global__ __launch_bounds__(256) void pack_kernel(const float* __restrict__ spk,
                                                   uint32_t* __restrict__ pk) {
    size_t g = (size_t)blockIdx.x * 256 + threadIdx.x;   // over 16384*512
    int row = (int)(g >> 9);
    int col = (int)(g & 511);
    float v = spk[(size_t)row * C3 + col];
    unsigned long long m = __ballot(v >= 0.5f);
    int lane = threadIdx.x & 63;
    if ((lane & 31) == 0)
        pk[(size_t)row * 16 + (col >> 5)] = (lane < 32) ? (uint32_t)m : (uint32_t)(m >> 32);
}

// ---------------------------------------------------------------------------
// 5a. softmax stats: am, Z per (t,b,l,head)
__global__ __launch_bounds__(256) void attn_sm(const uint32_t* __restrict__ pk,
                                               const int* __restrict__ idxws,
                                               float2* __restrict__ amz) {
    int bid = blockIdx.x;
    int hp = bid & 3, n = (bid >> 2) & 7, b = (bid >> 5) & 3, t = bid >> 7;
    __shared__ uint32_t kbs[2][512];
    int tid = threadIdx.x;
    int q = tid & 127, h = tid >> 7;
    int lbase = (t * BB + b) * LL;

    const int* ip = idxws + (b * NWIN + n) * TOPKN;
    int s0r = ip[0], s1r = ip[1], s2r = ip[2], s3r = ip[3];

#pragma unroll 4
    for (int e = tid; e < 1024; e += 256) {
        int hh = e >> 9, kk = e & 511;
        int w = kk >> 7;
        int sw = (w == 0) ? s0r : (w == 1) ? s1r : (w == 2) ? s2r : s3r;
        int row = sw * WIN + (kk & 127);
        kbs[hh][kk] = pk[(size_t)(lbase + row) * 16 + 8 + hp * 2 + hh];
    }
    uint32_t qw = pk[(size_t)(lbase + n * WIN + q) * 16 + hp * 2 + h];
    __syncthreads();

    const float ALPHA_SC = 0.17677669529663687f;   // hd^-0.5
    const uint4* kb4 = (const uint4*)kbs[h];
    int smax = 0;
#pragma unroll 8
    for (int k4 = 0; k4 < 128; ++k4) {
        uint4 w4 = kb4[k4];
        smax = max(smax, __popc(qw & w4.x));
        smax = max(smax, __popc(qw & w4.y));
        smax = max(smax, __popc(qw & w4.z));
        smax = max(smax, __popc(qw & w4.w));
    }
    float am = __fmul_rn((float)smax, ALPHA_SC);
    float Z = 0.0f;
#pragma unroll 4
    for (int k4 = 0; k4 < 128; ++k4) {
        uint4 w4 = kb4[k4];
        Z += expf(__fsub_rn(__fmul_rn((float)__popc(qw & w4.x), ALPHA_SC), am));
        Z += expf(__fsub_rn(__fmul_rn((float)__popc(qw & w4.y), ALPHA_SC), am));
        Z += expf(__fsub_rn(__fmul_rn((float)__popc(qw & w4.z), ALPHA_SC), am));
        Z += expf(__fsub_rn(__fmul_rn((float)__popc(qw & w4.w), ALPHA_SC), am));
    }
    amz[(size_t)(lbase + n * WIN + q) * HH + hp * 2 + h] = make_float2(am, Z);
}

// ---------------------------------------------------------------------------
// 5b. PV v9: Block = (t,b,n,hp,h): 1024 blocks, 256 threads = (q, dh).
//     SINGLE V window buffer in LDS (issue-early loads -> regs, write-late)
//     so LDS ~34.5 KB -> 4 blocks/CU resident = whole grid in one round.
__global__ __launch_bounds__(256, 4) void attn_pv(const float* __restrict__ spk,
                                                  const uint32_t* __restrict__ pk,
                                                  const int* __restrict__ idxws,
                                                  const float2* __restrict__ amz,
                                                  float* __restrict__ out) {
    int bid = blockIdx.x;
    int h = bid & 1, hp = (bid >> 1) & 3, n = (bid >> 3) & 7, b = (bid >> 6) & 3, t = bid >> 8;
    __shared__ float   Vlds[WIN][32];        // 16 KB, single buffer
    __shared__ float   ptab[33][WIN];        // 16.9 KB
    __shared__ uint32_t kbs[4 * WIN];        // 2 KB (this h only)
    int tid = threadIdx.x;
    int q = tid & 127, dh = tid >> 7;
    int lbase = (t * BB + b) * LL;

    const int* ip = idxws + (b * NWIN + n) * TOPKN;
    int s0r = ip[0], s1r = ip[1], s2r = ip[2], s3r = ip[3];

    // stage gathered K bit-words (this h)
#pragma unroll 2
    for (int e = tid; e < 512; e += 256) {
        int w = e >> 7;
        int sw = (w == 0) ? s0r : (w == 1) ? s1r : (w == 2) ? s2r : s3r;
        int row = sw * WIN + (e & 127);
        kbs[e] = pk[(size_t)(lbase + row) * 16 + 8 + hp * 2 + h];
    }
    uint32_t qw = pk[(size_t)(lbase + n * WIN + q) * 16 + hp * 2 + h];

    // P table: one column per q (dh==0 threads write; dh==1 shares)
    float2 az = amz[(size_t)(lbase + n * WIN + q) * HH + hp * 2 + h];
    const float ALPHA_SC = 0.17677669529663687f;   // hd^-0.5
    if (tid < 128) {
        for (int s = 0; s <= 32; ++s)
            ptab[s][tid] = expf(__fsub_rn(__fmul_rn((float)s, ALPHA_SC), az.x)) / az.y;
    }

    // V window source base (this block's 32-float slice per row)
    const float* vsrc = spk + (size_t)lbase * C3 + 512 + hp * 64 + h * 32;

    // prologue: stage window 0
    {
        const float* src = vsrc + (size_t)s0r * (WIN * C3);
        float4 st[4];
#pragma unroll
        for (int it = 0; it < 4; ++it) {
            int e = tid + it * 256;
            st[it] = *(const float4*)(src + (size_t)(e >> 3) * C3 + (e & 7) * 4);
        }
#pragma unroll
        for (int it = 0; it < 4; ++it) {
            int e = tid + it * 256;
            *(float4*)&Vlds[e >> 3][(e & 7) * 4] = st[it];
        }
    }
    __syncthreads();   // Vlds + kbs + ptab ready

    float acc[16];
#pragma unroll
    for (int d = 0; d < 16; ++d) acc[d] = 0.0f;

#pragma unroll
    for (int w = 0; w < 4; ++w) {
        // issue next window's loads early (latency hides under compute on w)
        float4 st[4];
        if (w < 3) {
            int swn = (w == 0) ? s1r : (w == 1) ? s2r : s3r;
            const float* src = vsrc + (size_t)swn * (WIN * C3);
#pragma unroll
            for (int it = 0; it < 4; ++it) {
                int e = tid + it * 256;
                st[it] = *(const float4*)(src + (size_t)(e >> 3) * C3 + (e & 7) * 4);
            }
        }

        // compute window w from Vlds (wave-uniform broadcast rows; 2-deep reg ring)
        const float* vb = &Vlds[0][dh * 16];
        const uint32_t* kw = kbs + w * 128;
        float4 Av[4], Bv[4];
#pragma unroll
        for (int u = 0; u < 4; ++u) Av[u] = ((const float4*)vb)[u];
#pragma unroll
        for (int u = 0; u < 4; ++u) Bv[u] = ((const float4*)(vb + 32))[u];
        float Pa = ptab[__popc(qw & kw[0])][q];
        float Pb = ptab[__popc(qw & kw[1])][q];

        for (int r = 0; r < 128; r += 2) {
            {
                float P = Pa;
                float4 v0 = Av[0], v1 = Av[1], v2 = Av[2], v3 = Av[3];
                const float4* pn = (const float4*)(vb + (size_t)((r + 2) & 127) * 32);
#pragma unroll
                for (int u = 0; u < 4; ++u) Av[u] = pn[u];
                Pa = ptab[__popc(qw & kw[(r + 2) & 127])][q];
                acc[ 0] = fmaf(P, v0.x, acc[ 0]);
                acc[ 1] = fmaf(P, v0.y, acc[ 1]);
                acc[ 2] = fmaf(P, v0.z, acc[ 2]);
                acc[ 3] = fmaf(P, v0.w, acc[ 3]);
                acc[ 4] = fmaf(P, v1.x, acc[ 4]);
                acc[ 5] = fmaf(P, v1.y, acc[ 5]);
                acc[ 6] = fmaf(P, v1.z, acc[ 6]);
                acc[ 7] = fmaf(P, v1.w, acc[ 7]);
                acc[ 8] = fmaf(P, v2.x, acc[ 8]);
                acc[ 9] = fmaf(P, v2.y, acc[ 9]);
                acc[10] = fmaf(P, v2.z, acc[10]);
                acc[11] = fmaf(P, v2.w, acc[11]);
                acc[12] = fmaf(P, v3.x, acc[12]);
                acc[13] = fmaf(P, v3.y, acc[13]);
                acc[14] = fmaf(P, v3.z, acc[14]);
                acc[15] = fmaf(P, v3.w, acc[15]);
            }
            {
                float P = Pb;
                float4 v0 = Bv[0], v1 = Bv[1], v2 = Bv[2], v3 = Bv[3];
                const float4* pn = (const float4*)(vb + (size_t)((r + 3) & 127) * 32);
#pragma unroll
                for (int u = 0; u < 4; ++u) Bv[u] = pn[u];
                Pb = ptab[__popc(qw & kw[(r + 3) & 127])][q];
                acc[ 0] = fmaf(P, v0.x, acc[ 0]);
                acc[ 1] = fmaf(P, v0.y, acc[ 1]);
                acc[ 2] = fmaf(P, v0.z, acc[ 2]);
                acc[ 3] = fmaf(P, v0.w, acc[ 3]);
                acc[ 4] = fmaf(P, v1.x, acc[ 4]);
                acc[ 5] = fmaf(P, v1.y, acc[ 5]);
                acc[ 6] = fmaf(P, v1.z, acc[ 6]);
                acc[ 7] = fmaf(P, v1.w, acc[ 7]);
                acc[ 8] = fmaf(P, v2.x, acc[ 8]);
                acc[ 9] = fmaf(P, v2.y, acc[ 9]);
                acc[10] = fmaf(P, v2.z, acc[10]);
                acc[11] = fmaf(P, v2.w, acc[11]);
                acc[12] = fmaf(P, v3.x, acc[12]);
                acc[13] = fmaf(P, v3.y, acc[13]);
                acc[14] = fmaf(P, v3.z, acc[14]);
                acc[15] = fmaf(P, v3.w, acc[15]);
            }
        }

        // write next window into the (single) buffer: barrier, write, barrier
        if (w < 3) {
            __syncthreads();   // everyone done reading window w
#pragma unroll
            for (int it = 0; it < 4; ++it) {
                int e = tid + it * 256;
                *(float4*)&Vlds[e >> 3][(e & 7) * 4] = st[it];
            }
            __syncthreads();   // window w+1 visible
        }
    }

    size_t obase = (size_t)(lbase + n * WIN + q) * CC + (hp * 2 + h) * 32 + dh * 16;
#pragma unroll
    for (int d = 0; d < 16; ++d) out[obase + d] = acc[d];
}

// ---------------------------------------------------------------------------
extern "C" void kernel_launch(void* const* d_in, const int* in_sizes, int n_in,
                              void* d_out, int out_size, void* d_ws, size_t ws_size,
                              hipStream_t stream) {
    const float* x      = (const float*)d_in[0];
    const float* w_qkv  = (const float*)d_in[1];
    const float* b_qkv  = (const float*)d_in[2];
    const float* w_proj = (const float*)d_in[3];
    const float* b_proj = (const float*)d_in[4];
    float* ws = (float*)d_ws;

    float* qkv      = ws;                 // 12582912 floats [T,B,L,3C] (spikes after LIF)
    float* attn_out = ws + 12582912;      // 4194304 floats [T,B,L,C]
    float* proj     = ws + 16777216;      // 4194304 floats [T,B,L,C]
    uint32_t* pkb   = (uint32_t*)proj;    // 262144 u32: aliases proj (dead before gemm_proj)
    float* region   = ws + 20971520;      // 8192 floats
    int*   idxp     = (int*)(ws + 20979712);  // 128 ints
    float2* amzp    = (float2*)(ws + 20979840); // 131072 float2 [T,B,L,H]
    float* outp     = (float*)d_out;

    region_kernel<<<dim3(BB * NWIN), dim3(256), 0, stream>>>(x, region);
    route_kernel<<<dim3(BB), dim3(64), 0, stream>>>(region, idxp);
    gemm_bias<<<dim3(128, 12), dim3(256), 0, stream>>>(x, w_qkv, b_qkv, qkv,
                                                       TT * BB * LL, C3, CC);
    lif_kernel<<<dim3(3072), dim3(256), 0, stream>>>(qkv, qkv, (size_t)BB * LL * C3);
    pack_kernel<<<dim3(32768), dim3(256), 0, stream>>>(qkv, pkb);
    attn_sm<<<dim3(TT * BB * NWIN * 4), dim3(256), 0, stream>>>(pkb, idxp, amzp);
    attn_pv<<<dim3(TT * BB * NWIN * 4 * 2), dim3(256), 0, stream>>>(qkv, pkb, idxp, amzp, attn_out);
    gemm_bias<<<dim3(128, 4), dim3(256), 0, stream>>>(attn_out, w_proj, b_proj, proj,
                                                      TT * BB * LL, CC, CC);
    lif_kernel<<<dim3(1024), dim3(256), 0, stream>>>(proj, outp, (size_t)BB * LL * CC);
}

// Round 10
// 300.342 us; speedup vs baseline: 1.8962x; 1.2049x over previous
//
#include <hip/hip_runtime.h>
#include <cstdint>
#include <cstddef>

#define TT 4
#define BB 4
#define LL 1024
#define CC 256
#define HH 8
#define HD 32
#define NWIN 8
#define WIN 128
#define TOPKN 4
#define C3 768

// ---------------------------------------------------------------------------
// 1. region sums
__global__ __launch_bounds__(256) void region_kernel(const float* __restrict__ x,
                                                     float* __restrict__ region) {
    int bn = blockIdx.x;          // b*NWIN + n
    int b = bn >> 3, n = bn & 7;
    int c = threadIdx.x;
    float tot = 0.0f;
    for (int r = 0; r < WIN; ++r) {
        int l = n * WIN + r;
        float s = 0.0f;
        for (int t = 0; t < TT; ++t) {
            s += x[(((size_t)t * BB + b) * LL + l) * CC + c];
        }
        tot += s;
    }
    region[(size_t)bn * CC + c] = tot;
}

// ---------------------------------------------------------------------------
// 2. routing
__global__ __launch_bounds__(64) void route_kernel(const float* __restrict__ region,
                                                   int* __restrict__ idx) {
    int b = blockIdx.x;
    __shared__ float reg[NWIN][CC];
    __shared__ float attn_r[NWIN][NWIN];
    int tid = threadIdx.x;
    for (int e = tid; e < NWIN * CC; e += 64)
        reg[e >> 8][e & 255] = region[(size_t)b * NWIN * CC + e];
    __syncthreads();
    int n = tid >> 3, m = tid & 7;
    float s = 0.0f;
    for (int c = 0; c < CC; ++c) s += reg[n][c] * reg[m][c];
    attn_r[n][m] = s * 0.0625f;   // C^-0.5 = 1/16 exact
    __syncthreads();
    if (tid < NWIN) {
        float vals[NWIN];
        for (int m2 = 0; m2 < NWIN; ++m2) vals[m2] = attn_r[tid][m2];
        for (int kk = 0; kk < TOPKN; ++kk) {
            int bi = 0; float bv = vals[0];
            for (int m2 = 1; m2 < NWIN; ++m2) {
                if (vals[m2] > bv) { bv = vals[m2]; bi = m2; }
            }
            idx[(b * NWIN + tid) * TOPKN + kk] = bi;
            vals[bi] = -INFINITY;
        }
    }
}

// ---------------------------------------------------------------------------
// 3. fp32 GEMM + bias (K ascending, exact)
__global__ __launch_bounds__(256) void gemm_bias(const float* __restrict__ A,
                                                 const float* __restrict__ W,
                                                 const float* __restrict__ bias,
                                                 float* __restrict__ C,
                                                 int M, int N, int K) {
    const int BM = 128, BN = 64, BK = 16, TM = 8, TN = 4;
    __shared__ float As[BK][BM + 4];
    __shared__ float Bs[BK][BN];
    int tid = threadIdx.x;
    int tx = tid & 15, ty = tid >> 4;
    int bm = blockIdx.x * BM, bn = blockIdx.y * BN;
    float acc[TM][TN] = {};
    for (int k0 = 0; k0 < K; k0 += BK) {
#pragma unroll
        for (int it = 0; it < 2; ++it) {
            int i = it * 256 + tid;
            int row = i >> 2, kc = (i & 3) * 4;
            float4 v = *(const float4*)(A + (size_t)(bm + row) * K + k0 + kc);
            As[kc + 0][row] = v.x; As[kc + 1][row] = v.y;
            As[kc + 2][row] = v.z; As[kc + 3][row] = v.w;
        }
        {
            int kr = tid >> 4, nc = (tid & 15) * 4;
            float4 v = *(const float4*)(W + (size_t)(k0 + kr) * N + bn + nc);
            *(float4*)&Bs[kr][nc] = v;
        }
        __syncthreads();
#pragma unroll
        for (int kk = 0; kk < BK; ++kk) {
            float a[TM], bb[TN];
            const float4* ap = (const float4*)&As[kk][ty * TM];
            float4 a0 = ap[0], a1 = ap[1];
            a[0]=a0.x; a[1]=a0.y; a[2]=a0.z; a[3]=a0.w;
            a[4]=a1.x; a[5]=a1.y; a[6]=a1.z; a[7]=a1.w;
            float4 b0 = *(const float4*)&Bs[kk][tx * TN];
            bb[0]=b0.x; bb[1]=b0.y; bb[2]=b0.z; bb[3]=b0.w;
#pragma unroll
            for (int i = 0; i < TM; ++i)
#pragma unroll
                for (int j = 0; j < TN; ++j)
                    acc[i][j] = fmaf(a[i], bb[j], acc[i][j]);
        }
        __syncthreads();
    }
#pragma unroll
    for (int i = 0; i < TM; ++i) {
        int row = bm + ty * TM + i;
#pragma unroll
        for (int j = 0; j < TN; ++j) {
            int col = bn + tx * TN + j;
            C[(size_t)row * N + col] = acc[i][j] + bias[col];
        }
    }
}

// ---------------------------------------------------------------------------
// 4. LIF over T
__global__ __launch_bounds__(256) void lif_kernel(const float* src, float* dst, size_t stride) {
    size_t i = ((size_t)blockIdx.x * blockDim.x + threadIdx.x) * 4;
    float v[4] = {0.f, 0.f, 0.f, 0.f};
    for (int t = 0; t < TT; ++t) {
        float4 xv4 = *(const float4*)(src + (size_t)t * stride + i);
        float xv[4] = {xv4.x, xv4.y, xv4.z, xv4.w};
        float sp[4];
#pragma unroll
        for (int j = 0; j < 4; ++j) {
            v[j] = v[j] + (xv[j] - v[j]) * 0.5f;
            bool fire = (v[j] >= 1.0f);
            sp[j] = fire ? 1.0f : 0.0f;
            v[j] = fire ? 0.0f : v[j];
        }
        *(float4*)(dst + (size_t)t * stride + i) = make_float4(sp[0], sp[1], sp[2], sp[3]);
    }
}

// ---------------------------------------------------------------------------
// 4b. pack Q/K spike bits
__global__ __launch_bounds__(256) void pack_kernel(const float* __restrict__ spk,
                                                   uint32_t* __restrict__ pk) {
    size_t g = (size_t)blockIdx.x * 256 + threadIdx.x;   // over 16384*512
    int row = (int)(g >> 9);
    int col = (int)(g & 511);
    float v = spk[(size_t)row * C3 + col];
    unsigned long long m = __ballot(v >= 0.5f);
    int lane = threadIdx.x & 63;
    if ((lane & 31) == 0)
        pk[(size_t)row * 16 + (col >> 5)] = (lane < 32) ? (uint32_t)m : (uint32_t)(m >> 32);
}

// ---------------------------------------------------------------------------
// 5a. softmax stats: am, Z per (t,b,l,head)
__global__ __launch_bounds__(256) void attn_sm(const uint32_t* __restrict__ pk,
                                               const int* __restrict__ idxws,
                                               float2* __restrict__ amz) {
    int bid = blockIdx.x;
    int hp = bid & 3, n = (bid >> 2) & 7, b = (bid >> 5) & 3, t = bid >> 7;
    __shared__ uint32_t kbs[2][512];
    int tid = threadIdx.x;
    int q = tid & 127, h = tid >> 7;
    int lbase = (t * BB + b) * LL;

    const int* ip = idxws + (b * NWIN + n) * TOPKN;
    int s0r = ip[0], s1r = ip[1], s2r = ip[2], s3r = ip[3];

#pragma unroll 4
    for (int e = tid; e < 1024; e += 256) {
        int hh = e >> 9, kk = e & 511;
        int w = kk >> 7;
        int sw = (w == 0) ? s0r : (w == 1) ? s1r : (w == 2) ? s2r : s3r;
        int row = sw * WIN + (kk & 127);
        kbs[hh][kk] = pk[(size_t)(lbase + row) * 16 + 8 + hp * 2 + hh];
    }
    uint32_t qw = pk[(size_t)(lbase + n * WIN + q) * 16 + hp * 2 + h];
    __syncthreads();

    const float ALPHA_SC = 0.17677669529663687f;   // hd^-0.5
    const uint4* kb4 = (const uint4*)kbs[h];
    int smax = 0;
#pragma unroll 8
    for (int k4 = 0; k4 < 128; ++k4) {
        uint4 w4 = kb4[k4];
        smax = max(smax, __popc(qw & w4.x));
        smax = max(smax, __popc(qw & w4.y));
        smax = max(smax, __popc(qw & w4.z));
        smax = max(smax, __popc(qw & w4.w));
    }
    float am = __fmul_rn((float)smax, ALPHA_SC);
    float Z = 0.0f;
#pragma unroll 4
    for (int k4 = 0; k4 < 128; ++k4) {
        uint4 w4 = kb4[k4];
        Z += expf(__fsub_rn(__fmul_rn((float)__popc(qw & w4.x), ALPHA_SC), am));
        Z += expf(__fsub_rn(__fmul_rn((float)__popc(qw & w4.y), ALPHA_SC), am));
        Z += expf(__fsub_rn(__fmul_rn((float)__popc(qw & w4.z), ALPHA_SC), am));
        Z += expf(__fsub_rn(__fmul_rn((float)__popc(qw & w4.w), ALPHA_SC), am));
    }
    amz[(size_t)(lbase + n * WIN + q) * HH + hp * 2 + h] = make_float2(am, Z);
}

// ---------------------------------------------------------------------------
// 5b. PV v10: Block = (t,b,n,hp,h): 1024 blocks, 256 threads = (q, dh).
//     Single 16KB V buffer (4 blocks/CU). Staging = short-lived regs between
//     two barriers (no spill). Inner loop: 4-row groups, uint4 kbs broadcast,
//     constant-offset ds_reads. FP chains identical (ascending k).
__global__ __launch_bounds__(256, 4) void attn_pv(const float* __restrict__ spk,
                                                  const uint32_t* __restrict__ pk,
                                                  const int* __restrict__ idxws,
                                                  const float2* __restrict__ amz,
                                                  float* __restrict__ out) {
    int bid = blockIdx.x;
    int h = bid & 1, hp = (bid >> 1) & 3, n = (bid >> 3) & 7, b = (bid >> 6) & 3, t = bid >> 8;
    __shared__ float    Vlds[WIN][32];       // 16 KB, single buffer
    __shared__ float    ptab[33][WIN];       // 16.9 KB
    __shared__ uint32_t kbs[4 * WIN];        // 2 KB (this h only)
    int tid = threadIdx.x;
    int q = tid & 127, dh = tid >> 7;
    int lbase = (t * BB + b) * LL;

    const int* ip = idxws + (b * NWIN + n) * TOPKN;
    int s0r = ip[0], s1r = ip[1], s2r = ip[2], s3r = ip[3];

    // stage gathered K bit-words (this h)
#pragma unroll 2
    for (int e = tid; e < 512; e += 256) {
        int w = e >> 7;
        int sw = (w == 0) ? s0r : (w == 1) ? s1r : (w == 2) ? s2r : s3r;
        int row = sw * WIN + (e & 127);
        kbs[e] = pk[(size_t)(lbase + row) * 16 + 8 + hp * 2 + h];
    }
    uint32_t qw = pk[(size_t)(lbase + n * WIN + q) * 16 + hp * 2 + h];

    // P table: one column per q (threads 0..127 write; dh==1 shares)
    float2 az = amz[(size_t)(lbase + n * WIN + q) * HH + hp * 2 + h];
    const float ALPHA_SC = 0.17677669529663687f;   // hd^-0.5
    if (tid < 128) {
        for (int s = 0; s <= 32; ++s)
            ptab[s][tid] = expf(__fsub_rn(__fmul_rn((float)s, ALPHA_SC), az.x)) / az.y;
    }

    // V window source: this block's 32-float slice per row; per-thread fixed lane
    const float* vsrc = spk + (size_t)lbase * C3 + 512 + hp * 64 + h * 32
                        + (size_t)(tid >> 3) * C3 + (tid & 7) * 4;
    float* vdst = &Vlds[tid >> 3][(tid & 7) * 4];

    float acc[16];
#pragma unroll
    for (int d = 0; d < 16; ++d) acc[d] = 0.0f;

    const uint4* kb4 = (const uint4*)kbs;
    const float* vb = &Vlds[0][dh * 16];

#pragma unroll
    for (int w = 0; w < 4; ++w) {
        // ---- stage window w (short-lived regs: load -> write, two barriers)
        {
            int sw = (w == 0) ? s0r : (w == 1) ? s1r : (w == 2) ? s2r : s3r;
            const float* src = vsrc + (size_t)sw * (WIN * C3);
            if (w) __syncthreads();          // all reads of window w-1 done
            float4 t0 = *(const float4*)(src);
            float4 t1 = *(const float4*)(src + 32 * C3);
            float4 t2 = *(const float4*)(src + 64 * C3);
            float4 t3 = *(const float4*)(src + 96 * C3);
            *(float4*)(vdst)              = t0;
            *(float4*)(vdst + 32 * 32)    = t1;
            *(float4*)(vdst + 64 * 32)    = t2;
            *(float4*)(vdst + 96 * 32)    = t3;
            __syncthreads();                 // window w (+ kbs/ptab on w==0) visible
        }

        // ---- compute window w: 32 groups of 4 rows
        const uint4* kw4 = kb4 + w * 32;
        const float* pr = vb;
#pragma unroll 2
        for (int g = 0; g < 32; ++g) {
            uint4 kw = kw4[g];
            float P0 = ptab[__popc(qw & kw.x)][q];
            float P1 = ptab[__popc(qw & kw.y)][q];
            float P2 = ptab[__popc(qw & kw.z)][q];
            float P3 = ptab[__popc(qw & kw.w)][q];
#pragma unroll
            for (int j = 0; j < 4; ++j) {
                float P = (j == 0) ? P0 : (j == 1) ? P1 : (j == 2) ? P2 : P3;
                const float4* vp = (const float4*)(pr + j * 32);
                float4 v0 = vp[0], v1 = vp[1], v2 = vp[2], v3 = vp[3];
                acc[ 0] = fmaf(P, v0.x, acc[ 0]);
                acc[ 1] = fmaf(P, v0.y, acc[ 1]);
                acc[ 2] = fmaf(P, v0.z, acc[ 2]);
                acc[ 3] = fmaf(P, v0.w, acc[ 3]);
                acc[ 4] = fmaf(P, v1.x, acc[ 4]);
                acc[ 5] = fmaf(P, v1.y, acc[ 5]);
                acc[ 6] = fmaf(P, v1.z, acc[ 6]);
                acc[ 7] = fmaf(P, v1.w, acc[ 7]);
                acc[ 8] = fmaf(P, v2.x, acc[ 8]);
                acc[ 9] = fmaf(P, v2.y, acc[ 9]);
                acc[10] = fmaf(P, v2.z, acc[10]);
                acc[11] = fmaf(P, v2.w, acc[11]);
                acc[12] = fmaf(P, v3.x, acc[12]);
                acc[13] = fmaf(P, v3.y, acc[13]);
                acc[14] = fmaf(P, v3.z, acc[14]);
                acc[15] = fmaf(P, v3.w, acc[15]);
            }
            pr += 128;   // next 4 rows
        }
    }

    size_t obase = (size_t)(lbase + n * WIN + q) * CC + (hp * 2 + h) * 32 + dh * 16;
#pragma unroll
    for (int d = 0; d < 16; ++d) out[obase + d] = acc[d];
}

// ---------------------------------------------------------------------------
extern "C" void kernel_launch(void* const* d_in, const int* in_sizes, int n_in,
                              void* d_out, int out_size, void* d_ws, size_t ws_size,
                              hipStream_t stream) {
    const float* x      = (const float*)d_in[0];
    const float* w_qkv  = (const float*)d_in[1];
    const float* b_qkv  = (const float*)d_in[2];
    const float* w_proj = (const float*)d_in[3];
    const float* b_proj = (const float*)d_in[4];
    float* ws = (float*)d_ws;

    float* qkv      = ws;                 // 12582912 floats [T,B,L,3C] (spikes after LIF)
    float* attn_out = ws + 12582912;      // 4194304 floats [T,B,L,C]
    float* proj     = ws + 16777216;      // 4194304 floats [T,B,L,C]
    uint32_t* pkb   = (uint32_t*)proj;    // 262144 u32: aliases proj (dead before gemm_proj)
    float* region   = ws + 20971520;      // 8192 floats
    int*   idxp     = (int*)(ws + 20979712);  // 128 ints
    float2* amzp    = (float2*)(ws + 20979840); // 131072 float2 [T,B,L,H]
    float* outp     = (float*)d_out;

    region_kernel<<<dim3(BB * NWIN), dim3(256), 0, stream>>>(x, region);
    route_kernel<<<dim3(BB), dim3(64), 0, stream>>>(region, idxp);
    gemm_bias<<<dim3(128, 12), dim3(256), 0, stream>>>(x, w_qkv, b_qkv, qkv,
                                                       TT * BB * LL, C3, CC);
    lif_kernel<<<dim3(3072), dim3(256), 0, stream>>>(qkv, qkv, (size_t)BB * LL * C3);
    pack_kernel<<<dim3(32768), dim3(256), 0, stream>>>(qkv, pkb);
    attn_sm<<<dim3(TT * BB * NWIN * 4), dim3(256), 0, stream>>>(pkb, idxp, amzp);
    attn_pv<<<dim3(TT * BB * NWIN * 4 * 2), dim3(256), 0, stream>>>(qkv, pkb, idxp, amzp, attn_out);
    gemm_bias<<<dim3(128, 4), dim3(256), 0, stream>>>(attn_out, w_proj, b_proj, proj,
                                                      TT * BB * LL, CC, CC);
    lif_kernel<<<dim3(1024), dim3(256), 0, stream>>>(proj, outp, (size_t)BB * LL * CC);
}

// Round 11
// 289.006 us; speedup vs baseline: 1.9706x; 1.0392x over previous
//
#include <hip/hip_runtime.h>
#include <cstdint>
#include <cstddef>

#define TT 4
#define BB 4
#define LL 1024
#define CC 256
#define HH 8
#define HD 32
#define NWIN 8
#define WIN 128
#define TOPKN 4
#define C3 768

// ---------------------------------------------------------------------------
// 1. region sums
__global__ __launch_bounds__(256) void region_kernel(const float* __restrict__ x,
                                                     float* __restrict__ region) {
    int bn = blockIdx.x;          // b*NWIN + n
    int b = bn >> 3, n = bn & 7;
    int c = threadIdx.x;
    float tot = 0.0f;
    for (int r = 0; r < WIN; ++r) {
        int l = n * WIN + r;
        float s = 0.0f;
        for (int t = 0; t < TT; ++t) {
            s += x[(((size_t)t * BB + b) * LL + l) * CC + c];
        }
        tot += s;
    }
    region[(size_t)bn * CC + c] = tot;
}

// ---------------------------------------------------------------------------
// 2. routing
__global__ __launch_bounds__(64) void route_kernel(const float* __restrict__ region,
                                                   int* __restrict__ idx) {
    int b = blockIdx.x;
    __shared__ float reg[NWIN][CC];
    __shared__ float attn_r[NWIN][NWIN];
    int tid = threadIdx.x;
    for (int e = tid; e < NWIN * CC; e += 64)
        reg[e >> 8][e & 255] = region[(size_t)b * NWIN * CC + e];
    __syncthreads();
    int n = tid >> 3, m = tid & 7;
    float s = 0.0f;
    for (int c = 0; c < CC; ++c) s += reg[n][c] * reg[m][c];
    attn_r[n][m] = s * 0.0625f;   // C^-0.5 = 1/16 exact
    __syncthreads();
    if (tid < NWIN) {
        float vals[NWIN];
        for (int m2 = 0; m2 < NWIN; ++m2) vals[m2] = attn_r[tid][m2];
        for (int kk = 0; kk < TOPKN; ++kk) {
            int bi = 0; float bv = vals[0];
            for (int m2 = 1; m2 < NWIN; ++m2) {
                if (vals[m2] > bv) { bv = vals[m2]; bi = m2; }
            }
            idx[(b * NWIN + tid) * TOPKN + kk] = bi;
            vals[bi] = -INFINITY;
        }
    }
}

// ---------------------------------------------------------------------------
// 3. fp32 GEMM + bias v2: BM=128 BN=128 BK=16, 256 threads, 8x8 micro-tile.
//    Per-output accumulation still one fma chain over k ascending -> bitwise same.
__global__ __launch_bounds__(256, 2) void gemm_bias(const float* __restrict__ A,
                                                    const float* __restrict__ W,
                                                    const float* __restrict__ bias,
                                                    float* __restrict__ C,
                                                    int M, int N, int K) {
    const int BM = 128, BN = 128, BK = 16, TM = 8, TN = 8;
    __shared__ float As[BK][BM + 4];
    __shared__ float Bs[BK][BN];
    int tid = threadIdx.x;
    int tx = tid & 15, ty = tid >> 4;
    int bm = blockIdx.x * BM, bn = blockIdx.y * BN;
    float acc[TM][TN] = {};
    for (int k0 = 0; k0 < K; k0 += BK) {
#pragma unroll
        for (int it = 0; it < 2; ++it) {
            int i = it * 256 + tid;
            int row = i >> 2, kc = (i & 3) * 4;
            float4 v = *(const float4*)(A + (size_t)(bm + row) * K + k0 + kc);
            As[kc + 0][row] = v.x; As[kc + 1][row] = v.y;
            As[kc + 2][row] = v.z; As[kc + 3][row] = v.w;
        }
#pragma unroll
        for (int it = 0; it < 2; ++it) {
            int i = it * 256 + tid;
            int kr = i >> 5, nc = (i & 31) * 4;
            float4 v = *(const float4*)(W + (size_t)(k0 + kr) * N + bn + nc);
            *(float4*)&Bs[kr][nc] = v;
        }
        __syncthreads();
#pragma unroll
        for (int kk = 0; kk < BK; ++kk) {
            float a[TM], bb[TN];
            const float4* ap = (const float4*)&As[kk][ty * TM];
            float4 a0 = ap[0], a1 = ap[1];
            a[0]=a0.x; a[1]=a0.y; a[2]=a0.z; a[3]=a0.w;
            a[4]=a1.x; a[5]=a1.y; a[6]=a1.z; a[7]=a1.w;
            const float4* bp = (const float4*)&Bs[kk][tx * TN];
            float4 b0 = bp[0], b1 = bp[1];
            bb[0]=b0.x; bb[1]=b0.y; bb[2]=b0.z; bb[3]=b0.w;
            bb[4]=b1.x; bb[5]=b1.y; bb[6]=b1.z; bb[7]=b1.w;
#pragma unroll
            for (int i = 0; i < TM; ++i)
#pragma unroll
                for (int j = 0; j < TN; ++j)
                    acc[i][j] = fmaf(a[i], bb[j], acc[i][j]);
        }
        __syncthreads();
    }
#pragma unroll
    for (int i = 0; i < TM; ++i) {
        int row = bm + ty * TM + i;
        int col = bn + tx * TN;
        float4 o0 = make_float4(acc[i][0] + bias[col + 0], acc[i][1] + bias[col + 1],
                                acc[i][2] + bias[col + 2], acc[i][3] + bias[col + 3]);
        float4 o1 = make_float4(acc[i][4] + bias[col + 4], acc[i][5] + bias[col + 5],
                                acc[i][6] + bias[col + 6], acc[i][7] + bias[col + 7]);
        *(float4*)&C[(size_t)row * N + col]     = o0;
        *(float4*)&C[(size_t)row * N + col + 4] = o1;
    }
}

// ---------------------------------------------------------------------------
// 4. LIF over T
__global__ __launch_bounds__(256) void lif_kernel(const float* src, float* dst, size_t stride) {
    size_t i = ((size_t)blockIdx.x * blockDim.x + threadIdx.x) * 4;
    float v[4] = {0.f, 0.f, 0.f, 0.f};
    for (int t = 0; t < TT; ++t) {
        float4 xv4 = *(const float4*)(src + (size_t)t * stride + i);
        float xv[4] = {xv4.x, xv4.y, xv4.z, xv4.w};
        float sp[4];
#pragma unroll
        for (int j = 0; j < 4; ++j) {
            v[j] = v[j] + (xv[j] - v[j]) * 0.5f;
            bool fire = (v[j] >= 1.0f);
            sp[j] = fire ? 1.0f : 0.0f;
            v[j] = fire ? 0.0f : v[j];
        }
        *(float4*)(dst + (size_t)t * stride + i) = make_float4(sp[0], sp[1], sp[2], sp[3]);
    }
}

// ---------------------------------------------------------------------------
// 4b. pack Q/K spike bits
__global__ __launch_bounds__(256) void pack_kernel(const float* __restrict__ spk,
                                                   uint32_t* __restrict__ pk) {
    size_t g = (size_t)blockIdx.x * 256 + threadIdx.x;   // over 16384*512
    int row = (int)(g >> 9);
    int col = (int)(g & 511);
    float v = spk[(size_t)row * C3 + col];
    unsigned long long m = __ballot(v >= 0.5f);
    int lane = threadIdx.x & 63;
    if ((lane & 31) == 0)
        pk[(size_t)row * 16 + (col >> 5)] = (lane < 32) ? (uint32_t)m : (uint32_t)(m >> 32);
}

// ---------------------------------------------------------------------------
// 5a. softmax stats: am, Z per (t,b,l,head)
__global__ __launch_bounds__(256) void attn_sm(const uint32_t* __restrict__ pk,
                                               const int* __restrict__ idxws,
                                               float2* __restrict__ amz) {
    int bid = blockIdx.x;
    int hp = bid & 3, n = (bid >> 2) & 7, b = (bid >> 5) & 3, t = bid >> 7;
    __shared__ uint32_t kbs[2][512];
    int tid = threadIdx.x;
    int q = tid & 127, h = tid >> 7;
    int lbase = (t * BB + b) * LL;

    const int* ip = idxws + (b * NWIN + n) * TOPKN;
    int s0r = ip[0], s1r = ip[1], s2r = ip[2], s3r = ip[3];

#pragma unroll 4
    for (int e = tid; e < 1024; e += 256) {
        int hh = e >> 9, kk = e & 511;
        int w = kk >> 7;
        int sw = (w == 0) ? s0r : (w == 1) ? s1r : (w == 2) ? s2r : s3r;
        int row = sw * WIN + (kk & 127);
        kbs[hh][kk] = pk[(size_t)(lbase + row) * 16 + 8 + hp * 2 + hh];
    }
    uint32_t qw = pk[(size_t)(lbase + n * WIN + q) * 16 + hp * 2 + h];
    __syncthreads();

    const float ALPHA_SC = 0.17677669529663687f;   // hd^-0.5
    const uint4* kb4 = (const uint4*)kbs[h];
    int smax = 0;
#pragma unroll 8
    for (int k4 = 0; k4 < 128; ++k4) {
        uint4 w4 = kb4[k4];
        smax = max(smax, __popc(qw & w4.x));
        smax = max(smax, __popc(qw & w4.y));
        smax = max(smax, __popc(qw & w4.z));
        smax = max(smax, __popc(qw & w4.w));
    }
    float am = __fmul_rn((float)smax, ALPHA_SC);
    float Z = 0.0f;
#pragma unroll 4
    for (int k4 = 0; k4 < 128; ++k4) {
        uint4 w4 = kb4[k4];
        Z += expf(__fsub_rn(__fmul_rn((float)__popc(qw & w4.x), ALPHA_SC), am));
        Z += expf(__fsub_rn(__fmul_rn((float)__popc(qw & w4.y), ALPHA_SC), am));
        Z += expf(__fsub_rn(__fmul_rn((float)__popc(qw & w4.z), ALPHA_SC), am));
        Z += expf(__fsub_rn(__fmul_rn((float)__popc(qw & w4.w), ALPHA_SC), am));
    }
    amz[(size_t)(lbase + n * WIN + q) * HH + hp * 2 + h] = make_float2(am, Z);
}

// ---------------------------------------------------------------------------
// 5b. PV v11: Block = (t,b,n,hp,h): 1024 blocks, 128 threads = (qg 0..63, dh 0..1).
//     Thread computes q in {qg, qg+64} x 16 d: each broadcast V read feeds 32 fma
//     (2x amortization), halving per-CU LDS issue. Single 16KB V buffer; T14
//     issue-early staging (regs live through compute; VGPR cap 256 -> no spill).
__global__ __launch_bounds__(128, 2) void attn_pv(const float* __restrict__ spk,
                                                  const uint32_t* __restrict__ pk,
                                                  const int* __restrict__ idxws,
                                                  const float2* __restrict__ amz,
                                                  float* __restrict__ out) {
    int bid = blockIdx.x;
    int h = bid & 1, hp = (bid >> 1) & 3, n = (bid >> 3) & 7, b = (bid >> 6) & 3, t = bid >> 8;
    __shared__ float    Vlds[WIN][32];       // 16 KB, single buffer
    __shared__ float    ptab[33][WIN];       // 16.9 KB
    __shared__ uint32_t kbs[4 * WIN];        // 2 KB (this h only)
    int tid = threadIdx.x;                   // 128 threads
    int qg = tid & 63, dh = tid >> 6;
    int lbase = (t * BB + b) * LL;

    const int* ip = idxws + (b * NWIN + n) * TOPKN;
    int s0r = ip[0], s1r = ip[1], s2r = ip[2], s3r = ip[3];

    // stage gathered K bit-words (this h): 512 words, 4 per thread
#pragma unroll 4
    for (int e = tid; e < 512; e += 128) {
        int w = e >> 7;
        int sw = (w == 0) ? s0r : (w == 1) ? s1r : (w == 2) ? s2r : s3r;
        int row = sw * WIN + (e & 127);
        kbs[e] = pk[(size_t)(lbase + row) * 16 + 8 + hp * 2 + h];
    }
    // two q-words per thread
    uint32_t qw0 = pk[(size_t)(lbase + n * WIN + qg) * 16 + hp * 2 + h];
    uint32_t qw1 = pk[(size_t)(lbase + n * WIN + qg + 64) * 16 + hp * 2 + h];

    // P table: thread writes column tid (one q each; 128 threads = 128 q)
    {
        float2 az = amz[(size_t)(lbase + n * WIN + tid) * HH + hp * 2 + h];
        const float ALPHA_SC = 0.17677669529663687f;   // hd^-0.5
        for (int s = 0; s <= 32; ++s)
            ptab[s][tid] = expf(__fsub_rn(__fmul_rn((float)s, ALPHA_SC), az.x)) / az.y;
    }

    // V staging geometry: 4096 floats/window, 32 per thread (8 x float4)
    const float* vsrc = spk + (size_t)lbase * C3 + 512 + hp * 64 + h * 32
                        + (size_t)(tid >> 3) * C3 + (tid & 7) * 4;
    float* vdst = &Vlds[tid >> 3][(tid & 7) * 4];

    float4 st[8];
    // prologue: stage window 0
    {
        const float* src = vsrc + (size_t)s0r * (WIN * C3);
#pragma unroll
        for (int it = 0; it < 8; ++it)
            st[it] = *(const float4*)(src + (size_t)it * 16 * C3);
#pragma unroll
        for (int it = 0; it < 8; ++it)
            *(float4*)(vdst + it * 16 * 32) = st[it];
    }
    __syncthreads();   // Vlds + kbs + ptab ready

    float acc0[16], acc1[16];
#pragma unroll
    for (int d = 0; d < 16; ++d) { acc0[d] = 0.0f; acc1[d] = 0.0f; }

    const uint4* kb4 = (const uint4*)kbs;
    const float* vb = &Vlds[0][dh * 16];

#pragma unroll
    for (int w = 0; w < 4; ++w) {
        // issue next window's loads early (hidden under this window's compute)
        if (w < 3) {
            int swn = (w == 0) ? s1r : (w == 1) ? s2r : s3r;
            const float* src = vsrc + (size_t)swn * (WIN * C3);
#pragma unroll
            for (int it = 0; it < 8; ++it)
                st[it] = *(const float4*)(src + (size_t)it * 16 * C3);
        }

        // compute window w: 32 groups of 4 rows, ascending k
        const uint4* kw4 = kb4 + w * 32;
        const float* pr = vb;
#pragma unroll 2
        for (int g = 0; g < 32; ++g) {
            uint4 kw = kw4[g];
#pragma unroll
            for (int j = 0; j < 4; ++j) {
                uint32_t kwj = (j == 0) ? kw.x : (j == 1) ? kw.y : (j == 2) ? kw.z : kw.w;
                float P0 = ptab[__popc(qw0 & kwj)][qg];
                float P1 = ptab[__popc(qw1 & kwj)][qg + 64];
                const float4* vp = (const float4*)(pr + j * 32);
                float4 v0 = vp[0], v1 = vp[1], v2 = vp[2], v3 = vp[3];
                acc0[ 0] = fmaf(P0, v0.x, acc0[ 0]);  acc1[ 0] = fmaf(P1, v0.x, acc1[ 0]);
                acc0[ 1] = fmaf(P0, v0.y, acc0[ 1]);  acc1[ 1] = fmaf(P1, v0.y, acc1[ 1]);
                acc0[ 2] = fmaf(P0, v0.z, acc0[ 2]);  acc1[ 2] = fmaf(P1, v0.z, acc1[ 2]);
                acc0[ 3] = fmaf(P0, v0.w, acc0[ 3]);  acc1[ 3] = fmaf(P1, v0.w, acc1[ 3]);
                acc0[ 4] = fmaf(P0, v1.x, acc0[ 4]);  acc1[ 4] = fmaf(P1, v1.x, acc1[ 4]);
                acc0[ 5] = fmaf(P0, v1.y, acc0[ 5]);  acc1[ 5] = fmaf(P1, v1.y, acc1[ 5]);
                acc0[ 6] = fmaf(P0, v1.z, acc0[ 6]);  acc1[ 6] = fmaf(P1, v1.z, acc1[ 6]);
                acc0[ 7] = fmaf(P0, v1.w, acc0[ 7]);  acc1[ 7] = fmaf(P1, v1.w, acc1[ 7]);
                acc0[ 8] = fmaf(P0, v2.x, acc0[ 8]);  acc1[ 8] = fmaf(P1, v2.x, acc1[ 8]);
                acc0[ 9] = fmaf(P0, v2.y, acc0[ 9]);  acc1[ 9] = fmaf(P1, v2.y, acc1[ 9]);
                acc0[10] = fmaf(P0, v2.z, acc0[10]);  acc1[10] = fmaf(P1, v2.z, acc1[10]);
                acc0[11] = fmaf(P0, v2.w, acc0[11]);  acc1[11] = fmaf(P1, v2.w, acc1[11]);
                acc0[12] = fmaf(P0, v3.x, acc0[12]);  acc1[12] = fmaf(P1, v3.x, acc1[12]);
                acc0[13] = fmaf(P0, v3.y, acc0[13]);  acc1[13] = fmaf(P1, v3.y, acc1[13]);
                acc0[14] = fmaf(P0, v3.z, acc0[14]);  acc1[14] = fmaf(P1, v3.z, acc1[14]);
                acc0[15] = fmaf(P0, v3.w, acc0[15]);  acc1[15] = fmaf(P1, v3.w, acc1[15]);
            }
            pr += 128;   // next 4 rows
        }

        // write next window, two barriers around the overwrite
        if (w < 3) {
            __syncthreads();   // all reads of window w done
#pragma unroll
            for (int it = 0; it < 8; ++it)
                *(float4*)(vdst + it * 16 * 32) = st[it];
            __syncthreads();   // window w+1 visible
        }
    }

    size_t ob0 = (size_t)(lbase + n * WIN + qg) * CC + (hp * 2 + h) * 32 + dh * 16;
    size_t ob1 = ob0 + (size_t)64 * CC;
#pragma unroll
    for (int d = 0; d < 16; ++d) out[ob0 + d] = acc0[d];
#pragma unroll
    for (int d = 0; d < 16; ++d) out[ob1 + d] = acc1[d];
}

// ---------------------------------------------------------------------------
extern "C" void kernel_launch(void* const* d_in, const int* in_sizes, int n_in,
                              void* d_out, int out_size, void* d_ws, size_t ws_size,
                              hipStream_t stream) {
    const float* x      = (const float*)d_in[0];
    const float* w_qkv  = (const float*)d_in[1];
    const float* b_qkv  = (const float*)d_in[2];
    const float* w_proj = (const float*)d_in[3];
    const float* b_proj = (const float*)d_in[4];
    float* ws = (float*)d_ws;

    float* qkv      = ws;                 // 12582912 floats [T,B,L,3C] (spikes after LIF)
    float* attn_out = ws + 12582912;      // 4194304 floats [T,B,L,C]
    float* proj     = ws + 16777216;      // 4194304 floats [T,B,L,C]
    uint32_t* pkb   = (uint32_t*)proj;    // 262144 u32: aliases proj (dead before gemm_proj)
    float* region   = ws + 20971520;      // 8192 floats
    int*   idxp     = (int*)(ws + 20979712);  // 128 ints
    float2* amzp    = (float2*)(ws + 20979840); // 131072 float2 [T,B,L,H]
    float* outp     = (float*)d_out;

    region_kernel<<<dim3(BB * NWIN), dim3(256), 0, stream>>>(x, region);
    route_kernel<<<dim3(BB), dim3(64), 0, stream>>>(region, idxp);
    gemm_bias<<<dim3(128, 6), dim3(256), 0, stream>>>(x, w_qkv, b_qkv, qkv,
                                                      TT * BB * LL, C3, CC);
    lif_kernel<<<dim3(3072), dim3(256), 0, stream>>>(qkv, qkv, (size_t)BB * LL * C3);
    pack_kernel<<<dim3(32768), dim3(256), 0, stream>>>(qkv, pkb);
    attn_sm<<<dim3(TT * BB * NWIN * 4), dim3(256), 0, stream>>>(pkb, idxp, amzp);
    attn_pv<<<dim3(TT * BB * NWIN * 4 * 2), dim3(128), 0, stream>>>(qkv, pkb, idxp, amzp, attn_out);
    gemm_bias<<<dim3(128, 2), dim3(256), 0, stream>>>(attn_out, w_proj, b_proj, proj,
                                                      TT * BB * LL, CC, CC);
    lif_kernel<<<dim3(1024), dim3(256), 0, stream>>>(proj, outp, (size_t)BB * LL * CC);
}

// Round 12
// 286.492 us; speedup vs baseline: 1.9879x; 1.0088x over previous
//
#include <hip/hip_runtime.h>
#include <cstdint>
#include <cstddef>

#define TT 4
#define BB 4
#define LL 1024
#define CC 256
#define HH 8
#define HD 32
#define NWIN 8
#define WIN 128
#define TOPKN 4
#define C3 768

// ---------------------------------------------------------------------------
// 1. region sums
__global__ __launch_bounds__(256) void region_kernel(const float* __restrict__ x,
                                                     float* __restrict__ region) {
    int bn = blockIdx.x;          // b*NWIN + n
    int b = bn >> 3, n = bn & 7;
    int c = threadIdx.x;
    float tot = 0.0f;
    for (int r = 0; r < WIN; ++r) {
        int l = n * WIN + r;
        float s = 0.0f;
        for (int t = 0; t < TT; ++t) {
            s += x[(((size_t)t * BB + b) * LL + l) * CC + c];
        }
        tot += s;
    }
    region[(size_t)bn * CC + c] = tot;
}

// ---------------------------------------------------------------------------
// 2. routing
__global__ __launch_bounds__(64) void route_kernel(const float* __restrict__ region,
                                                   int* __restrict__ idx) {
    int b = blockIdx.x;
    __shared__ float reg[NWIN][CC];
    __shared__ float attn_r[NWIN][NWIN];
    int tid = threadIdx.x;
    for (int e = tid; e < NWIN * CC; e += 64)
        reg[e >> 8][e & 255] = region[(size_t)b * NWIN * CC + e];
    __syncthreads();
    int n = tid >> 3, m = tid & 7;
    float s = 0.0f;
    for (int c = 0; c < CC; ++c) s += reg[n][c] * reg[m][c];
    attn_r[n][m] = s * 0.0625f;   // C^-0.5 = 1/16 exact
    __syncthreads();
    if (tid < NWIN) {
        float vals[NWIN];
        for (int m2 = 0; m2 < NWIN; ++m2) vals[m2] = attn_r[tid][m2];
        for (int kk = 0; kk < TOPKN; ++kk) {
            int bi = 0; float bv = vals[0];
            for (int m2 = 1; m2 < NWIN; ++m2) {
                if (vals[m2] > bv) { bv = vals[m2]; bi = m2; }
            }
            idx[(b * NWIN + tid) * TOPKN + kk] = bi;
            vals[bi] = -INFINITY;
        }
    }
}

// ---------------------------------------------------------------------------
// 3. fp32 GEMM + bias: BM=128 BN=128 BK=16, 256 threads, 8x8 micro-tile.
__global__ __launch_bounds__(256, 2) void gemm_bias(const float* __restrict__ A,
                                                    const float* __restrict__ W,
                                                    const float* __restrict__ bias,
                                                    float* __restrict__ C,
                                                    int M, int N, int K) {
    const int BM = 128, BN = 128, BK = 16, TM = 8, TN = 8;
    __shared__ float As[BK][BM + 4];
    __shared__ float Bs[BK][BN];
    int tid = threadIdx.x;
    int tx = tid & 15, ty = tid >> 4;
    int bm = blockIdx.x * BM, bn = blockIdx.y * BN;
    float acc[TM][TN] = {};
    for (int k0 = 0; k0 < K; k0 += BK) {
#pragma unroll
        for (int it = 0; it < 2; ++it) {
            int i = it * 256 + tid;
            int row = i >> 2, kc = (i & 3) * 4;
            float4 v = *(const float4*)(A + (size_t)(bm + row) * K + k0 + kc);
            As[kc + 0][row] = v.x; As[kc + 1][row] = v.y;
            As[kc + 2][row] = v.z; As[kc + 3][row] = v.w;
        }
#pragma unroll
        for (int it = 0; it < 2; ++it) {
            int i = it * 256 + tid;
            int kr = i >> 5, nc = (i & 31) * 4;
            float4 v = *(const float4*)(W + (size_t)(k0 + kr) * N + bn + nc);
            *(float4*)&Bs[kr][nc] = v;
        }
        __syncthreads();
#pragma unroll
        for (int kk = 0; kk < BK; ++kk) {
            float a[TM], bb[TN];
            const float4* ap = (const float4*)&As[kk][ty * TM];
            float4 a0 = ap[0], a1 = ap[1];
            a[0]=a0.x; a[1]=a0.y; a[2]=a0.z; a[3]=a0.w;
            a[4]=a1.x; a[5]=a1.y; a[6]=a1.z; a[7]=a1.w;
            const float4* bp = (const float4*)&Bs[kk][tx * TN];
            float4 b0 = bp[0], b1 = bp[1];
            bb[0]=b0.x; bb[1]=b0.y; bb[2]=b0.z; bb[3]=b0.w;
            bb[4]=b1.x; bb[5]=b1.y; bb[6]=b1.z; bb[7]=b1.w;
#pragma unroll
            for (int i = 0; i < TM; ++i)
#pragma unroll
                for (int j = 0; j < TN; ++j)
                    acc[i][j] = fmaf(a[i], bb[j], acc[i][j]);
        }
        __syncthreads();
    }
#pragma unroll
    for (int i = 0; i < TM; ++i) {
        int row = bm + ty * TM + i;
        int col = bn + tx * TN;
        float4 o0 = make_float4(acc[i][0] + bias[col + 0], acc[i][1] + bias[col + 1],
                                acc[i][2] + bias[col + 2], acc[i][3] + bias[col + 3]);
        float4 o1 = make_float4(acc[i][4] + bias[col + 4], acc[i][5] + bias[col + 5],
                                acc[i][6] + bias[col + 6], acc[i][7] + bias[col + 7]);
        *(float4*)&C[(size_t)row * N + col]     = o0;
        *(float4*)&C[(size_t)row * N + col + 4] = o1;
    }
}

// ---------------------------------------------------------------------------
// 4. LIF over T
__global__ __launch_bounds__(256) void lif_kernel(const float* src, float* dst, size_t stride) {
    size_t i = ((size_t)blockIdx.x * blockDim.x + threadIdx.x) * 4;
    float v[4] = {0.f, 0.f, 0.f, 0.f};
    for (int t = 0; t < TT; ++t) {
        float4 xv4 = *(const float4*)(src + (size_t)t * stride + i);
        float xv[4] = {xv4.x, xv4.y, xv4.z, xv4.w};
        float sp[4];
#pragma unroll
        for (int j = 0; j < 4; ++j) {
            v[j] = v[j] + (xv[j] - v[j]) * 0.5f;
            bool fire = (v[j] >= 1.0f);
            sp[j] = fire ? 1.0f : 0.0f;
            v[j] = fire ? 0.0f : v[j];
        }
        *(float4*)(dst + (size_t)t * stride + i) = make_float4(sp[0], sp[1], sp[2], sp[3]);
    }
}

// ---------------------------------------------------------------------------
// 4b. pack Q/K spike bits
__global__ __launch_bounds__(256) void pack_kernel(const float* __restrict__ spk,
                                                   uint32_t* __restrict__ pk) {
    size_t g = (size_t)blockIdx.x * 256 + threadIdx.x;   // over 16384*512
    int row = (int)(g >> 9);
    int col = (int)(g & 511);
    float v = spk[(size_t)row * C3 + col];
    unsigned long long m = __ballot(v >= 0.5f);
    int lane = threadIdx.x & 63;
    if ((lane & 31) == 0)
        pk[(size_t)row * 16 + (col >> 5)] = (lane < 32) ? (uint32_t)m : (uint32_t)(m >> 32);
}

// ---------------------------------------------------------------------------
// 5a. softmax stats: am, Z per (t,b,l,head)
__global__ __launch_bounds__(256) void attn_sm(const uint32_t* __restrict__ pk,
                                               const int* __restrict__ idxws,
                                               float2* __restrict__ amz) {
    int bid = blockIdx.x;
    int hp = bid & 3, n = (bid >> 2) & 7, b = (bid >> 5) & 3, t = bid >> 7;
    __shared__ uint32_t kbs[2][512];
    int tid = threadIdx.x;
    int q = tid & 127, h = tid >> 7;
    int lbase = (t * BB + b) * LL;

    const int* ip = idxws + (b * NWIN + n) * TOPKN;
    int s0r = ip[0], s1r = ip[1], s2r = ip[2], s3r = ip[3];

#pragma unroll 4
    for (int e = tid; e < 1024; e += 256) {
        int hh = e >> 9, kk = e & 511;
        int w = kk >> 7;
        int sw = (w == 0) ? s0r : (w == 1) ? s1r : (w == 2) ? s2r : s3r;
        int row = sw * WIN + (kk & 127);
        kbs[hh][kk] = pk[(size_t)(lbase + row) * 16 + 8 + hp * 2 + hh];
    }
    uint32_t qw = pk[(size_t)(lbase + n * WIN + q) * 16 + hp * 2 + h];
    __syncthreads();

    const float ALPHA_SC = 0.17677669529663687f;   // hd^-0.5
    const uint4* kb4 = (const uint4*)kbs[h];
    int smax = 0;
#pragma unroll 8
    for (int k4 = 0; k4 < 128; ++k4) {
        uint4 w4 = kb4[k4];
        smax = max(smax, __popc(qw & w4.x));
        smax = max(smax, __popc(qw & w4.y));
        smax = max(smax, __popc(qw & w4.z));
        smax = max(smax, __popc(qw & w4.w));
    }
    float am = __fmul_rn((float)smax, ALPHA_SC);
    float Z = 0.0f;
#pragma unroll 4
    for (int k4 = 0; k4 < 128; ++k4) {
        uint4 w4 = kb4[k4];
        Z += expf(__fsub_rn(__fmul_rn((float)__popc(qw & w4.x), ALPHA_SC), am));
        Z += expf(__fsub_rn(__fmul_rn((float)__popc(qw & w4.y), ALPHA_SC), am));
        Z += expf(__fsub_rn(__fmul_rn((float)__popc(qw & w4.z), ALPHA_SC), am));
        Z += expf(__fsub_rn(__fmul_rn((float)__popc(qw & w4.w), ALPHA_SC), am));
    }
    amz[(size_t)(lbase + n * WIN + q) * HH + hp * 2 + h] = make_float2(am, Z);
}

// ---------------------------------------------------------------------------
// 5b. PV v12: Block = (t,b,n,hp,h): 1024 blocks, 128 threads = (qg, dh).
//     V staged via global_load_lds DMA (no staging registers -> nothing to spill),
//     64-row half-windows double-buffered (2x8KB). Thread computes q in {qg,qg+64}
//     x 16 d. FP chains identical (ascending k) -> bitwise exact.
__global__ __launch_bounds__(128, 2) void attn_pv(const float* __restrict__ spk,
                                                  const uint32_t* __restrict__ pk,
                                                  const int* __restrict__ idxws,
                                                  const float2* __restrict__ amz,
                                                  float* __restrict__ out) {
    int bid = blockIdx.x;
    int h = bid & 1, hp = (bid >> 1) & 3, n = (bid >> 3) & 7, b = (bid >> 6) & 3, t = bid >> 8;
    __shared__ __align__(16) float Vlds[2][64][32];   // 2 x 8 KB half-window buffers
    __shared__ float    ptab[33][WIN];                // 16.9 KB
    __shared__ uint32_t kbs[4 * WIN];                 // 2 KB (this h only)
    int tid = threadIdx.x;                            // 128 threads
    int qg = tid & 63, dh = tid >> 6;
    int lbase = (t * BB + b) * LL;

    const int* ip = idxws + (b * NWIN + n) * TOPKN;
    int sidx[TOPKN];
    sidx[0] = ip[0]; sidx[1] = ip[1]; sidx[2] = ip[2]; sidx[3] = ip[3];

    // stage gathered K bit-words (this h): 512 words, 4 per thread
#pragma unroll 4
    for (int e = tid; e < 512; e += 128) {
        int w = e >> 7;
        int sw = sidx[w];
        int row = sw * WIN + (e & 127);
        kbs[e] = pk[(size_t)(lbase + row) * 16 + 8 + hp * 2 + h];
    }
    // two q-words per thread
    uint32_t qw0 = pk[(size_t)(lbase + n * WIN + qg) * 16 + hp * 2 + h];
    uint32_t qw1 = pk[(size_t)(lbase + n * WIN + qg + 64) * 16 + hp * 2 + h];

    // P table: thread writes column tid (one q each; 128 threads = 128 q)
    {
        float2 az = amz[(size_t)(lbase + n * WIN + tid) * HH + hp * 2 + h];
        const float ALPHA_SC = 0.17677669529663687f;   // hd^-0.5
        for (int s = 0; s <= 32; ++s)
            ptab[s][tid] = expf(__fsub_rn(__fmul_rn((float)s, ALPHA_SC), az.x)) / az.y;
    }

    // V staging: per-lane global source, wave-uniform LDS base + lane*16 (DMA rule).
    // half hw covers window hw>>1, rows (hw&1)*64 .. +63. Thread tid's source rows:
    // (tid>>3) + it*16; LDS byte offset = it*2048 + tid*16 (= wave-uniform + lane*16).
    const float* vsrc = spk + (size_t)lbase * C3 + 512 + hp * 64 + h * 32
                        + (size_t)(tid >> 3) * C3 + (tid & 7) * 4;
    int wvoff = (tid >> 6) * 1024;   // wave-uniform within each wave

#define STAGE_HALF(hw_)                                                              \
    do {                                                                             \
        int hw = (hw_);                                                              \
        const float* src = vsrc + (size_t)sidx[hw >> 1] * (WIN * C3)                 \
                                + (size_t)(hw & 1) * 64 * C3;                        \
        char* lbasep = (char*)(&Vlds[hw & 1][0][0]) + wvoff;                         \
        _Pragma("unroll")                                                            \
        for (int it = 0; it < 4; ++it) {                                             \
            __builtin_amdgcn_global_load_lds(                                        \
                (const __attribute__((address_space(1))) void*)(src + (size_t)it * 16 * C3), \
                (__attribute__((address_space(3))) void*)(lbasep + it * 2048),       \
                16, 0, 0);                                                           \
        }                                                                            \
    } while (0)

    // prologue: DMA half 0
    STAGE_HALF(0);

    float acc0[16], acc1[16];
#pragma unroll
    for (int d = 0; d < 16; ++d) { acc0[d] = 0.0f; acc1[d] = 0.0f; }

    asm volatile("s_waitcnt vmcnt(0)" ::: "memory");
    __syncthreads();   // half0 + kbs + ptab ready

    const uint4* kb4 = (const uint4*)kbs;

#pragma unroll
    for (int hw = 0; hw < 8; ++hw) {
        // DMA next half into the other buffer (in flight during this compute)
        if (hw < 7) STAGE_HALF(hw + 1);

        // compute half hw: 16 groups of 4 rows, ascending k
        const uint4* kw4 = kb4 + hw * 16;
        const float* pr = &Vlds[hw & 1][0][dh * 16];
#pragma unroll 4
        for (int g = 0; g < 16; ++g) {
            uint4 kw = kw4[g];
#pragma unroll
            for (int j = 0; j < 4; ++j) {
                uint32_t kwj = (j == 0) ? kw.x : (j == 1) ? kw.y : (j == 2) ? kw.z : kw.w;
                float P0 = ptab[__popc(qw0 & kwj)][qg];
                float P1 = ptab[__popc(qw1 & kwj)][qg + 64];
                const float4* vp = (const float4*)(pr + j * 32);
                float4 v0 = vp[0], v1 = vp[1], v2 = vp[2], v3 = vp[3];
                acc0[ 0] = fmaf(P0, v0.x, acc0[ 0]);  acc1[ 0] = fmaf(P1, v0.x, acc1[ 0]);
                acc0[ 1] = fmaf(P0, v0.y, acc0[ 1]);  acc1[ 1] = fmaf(P1, v0.y, acc1[ 1]);
                acc0[ 2] = fmaf(P0, v0.z, acc0[ 2]);  acc1[ 2] = fmaf(P1, v0.z, acc1[ 2]);
                acc0[ 3] = fmaf(P0, v0.w, acc0[ 3]);  acc1[ 3] = fmaf(P1, v0.w, acc1[ 3]);
                acc0[ 4] = fmaf(P0, v1.x, acc0[ 4]);  acc1[ 4] = fmaf(P1, v1.x, acc1[ 4]);
                acc0[ 5] = fmaf(P0, v1.y, acc0[ 5]);  acc1[ 5] = fmaf(P1, v1.y, acc1[ 5]);
                acc0[ 6] = fmaf(P0, v1.z, acc0[ 6]);  acc1[ 6] = fmaf(P1, v1.z, acc1[ 6]);
                acc0[ 7] = fmaf(P0, v1.w, acc0[ 7]);  acc1[ 7] = fmaf(P1, v1.w, acc1[ 7]);
                acc0[ 8] = fmaf(P0, v2.x, acc0[ 8]);  acc1[ 8] = fmaf(P1, v2.x, acc1[ 8]);
                acc0[ 9] = fmaf(P0, v2.y, acc0[ 9]);  acc1[ 9] = fmaf(P1, v2.y, acc1[ 9]);
                acc0[10] = fmaf(P0, v2.z, acc0[10]);  acc1[10] = fmaf(P1, v2.z, acc1[10]);
                acc0[11] = fmaf(P0, v2.w, acc0[11]);  acc1[11] = fmaf(P1, v2.w, acc1[11]);
                acc0[12] = fmaf(P0, v3.x, acc0[12]);  acc1[12] = fmaf(P1, v3.x, acc1[12]);
                acc0[13] = fmaf(P0, v3.y, acc0[13]);  acc1[13] = fmaf(P1, v3.y, acc1[13]);
                acc0[14] = fmaf(P0, v3.z, acc0[14]);  acc1[14] = fmaf(P1, v3.z, acc1[14]);
                acc0[15] = fmaf(P0, v3.w, acc0[15]);  acc1[15] = fmaf(P1, v3.w, acc1[15]);
            }
            pr += 128;   // next 4 rows
        }

        // drain next-half DMA + release this buffer for hw+2's DMA
        asm volatile("s_waitcnt vmcnt(0)" ::: "memory");
        __syncthreads();
    }
#undef STAGE_HALF

    size_t ob0 = (size_t)(lbase + n * WIN + qg) * CC + (hp * 2 + h) * 32 + dh * 16;
    size_t ob1 = ob0 + (size_t)64 * CC;
#pragma unroll
    for (int d = 0; d < 16; ++d) out[ob0 + d] = acc0[d];
#pragma unroll
    for (int d = 0; d < 16; ++d) out[ob1 + d] = acc1[d];
}

// ---------------------------------------------------------------------------
extern "C" void kernel_launch(void* const* d_in, const int* in_sizes, int n_in,
                              void* d_out, int out_size, void* d_ws, size_t ws_size,
                              hipStream_t stream) {
    const float* x      = (const float*)d_in[0];
    const float* w_qkv  = (const float*)d_in[1];
    const float* b_qkv  = (const float*)d_in[2];
    const float* w_proj = (const float*)d_in[3];
    const float* b_proj = (const float*)d_in[4];
    float* ws = (float*)d_ws;

    float* qkv      = ws;                 // 12582912 floats [T,B,L,3C] (spikes after LIF)
    float* attn_out = ws + 12582912;      // 4194304 floats [T,B,L,C]
    float* proj     = ws + 16777216;      // 4194304 floats [T,B,L,C]
    uint32_t* pkb   = (uint32_t*)proj;    // 262144 u32: aliases proj (dead before gemm_proj)
    float* region   = ws + 20971520;      // 8192 floats
    int*   idxp     = (int*)(ws + 20979712);  // 128 ints
    float2* amzp    = (float2*)(ws + 20979840); // 131072 float2 [T,B,L,H]
    float* outp     = (float*)d_out;

    region_kernel<<<dim3(BB * NWIN), dim3(256), 0, stream>>>(x, region);
    route_kernel<<<dim3(BB), dim3(64), 0, stream>>>(region, idxp);
    gemm_bias<<<dim3(128, 6), dim3(256), 0, stream>>>(x, w_qkv, b_qkv, qkv,
                                                      TT * BB * LL, C3, CC);
    lif_kernel<<<dim3(3072), dim3(256), 0, stream>>>(qkv, qkv, (size_t)BB * LL * C3);
    pack_kernel<<<dim3(32768), dim3(256), 0, stream>>>(qkv, pkb);
    attn_sm<<<dim3(TT * BB * NWIN * 4), dim3(256), 0, stream>>>(pkb, idxp, amzp);
    attn_pv<<<dim3(TT * BB * NWIN * 4 * 2), dim3(128), 0, stream>>>(qkv, pkb, idxp, amzp, attn_out);
    gemm_bias<<<dim3(128, 2), dim3(256), 0, stream>>>(attn_out, w_proj, b_proj, proj,
                                                      TT * BB * LL, CC, CC);
    lif_kernel<<<dim3(1024), dim3(256), 0, stream>>>(proj, outp, (size_t)BB * LL * CC);
}

// Round 13
// 274.536 us; speedup vs baseline: 2.0744x; 1.0435x over previous
//
#include <hip/hip_runtime.h>
#include <cstdint>
#include <cstddef>

#define TT 4
#define BB 4
#define LL 1024
#define CC 256
#define HH 8
#define HD 32
#define NWIN 8
#define WIN 128
#define TOPKN 4
#define C3 768

// ---------------------------------------------------------------------------
// 1. region sums
__global__ __launch_bounds__(256) void region_kernel(const float* __restrict__ x,
                                                     float* __restrict__ region) {
    int bn = blockIdx.x;          // b*NWIN + n
    int b = bn >> 3, n = bn & 7;
    int c = threadIdx.x;
    float tot = 0.0f;
    for (int r = 0; r < WIN; ++r) {
        int l = n * WIN + r;
        float s = 0.0f;
        for (int t = 0; t < TT; ++t) {
            s += x[(((size_t)t * BB + b) * LL + l) * CC + c];
        }
        tot += s;
    }
    region[(size_t)bn * CC + c] = tot;
}

// ---------------------------------------------------------------------------
// 2. routing
__global__ __launch_bounds__(64) void route_kernel(const float* __restrict__ region,
                                                   int* __restrict__ idx) {
    int b = blockIdx.x;
    __shared__ float reg[NWIN][CC];
    __shared__ float attn_r[NWIN][NWIN];
    int tid = threadIdx.x;
    for (int e = tid; e < NWIN * CC; e += 64)
        reg[e >> 8][e & 255] = region[(size_t)b * NWIN * CC + e];
    __syncthreads();
    int n = tid >> 3, m = tid & 7;
    float s = 0.0f;
    for (int c = 0; c < CC; ++c) s += reg[n][c] * reg[m][c];
    attn_r[n][m] = s * 0.0625f;   // C^-0.5 = 1/16 exact
    __syncthreads();
    if (tid < NWIN) {
        float vals[NWIN];
        for (int m2 = 0; m2 < NWIN; ++m2) vals[m2] = attn_r[tid][m2];
        for (int kk = 0; kk < TOPKN; ++kk) {
            int bi = 0; float bv = vals[0];
            for (int m2 = 1; m2 < NWIN; ++m2) {
                if (vals[m2] > bv) { bv = vals[m2]; bi = m2; }
            }
            idx[(b * NWIN + tid) * TOPKN + kk] = bi;
            vals[bi] = -INFINITY;
        }
    }
}

// ---------------------------------------------------------------------------
// 3a. fp32 GEMM + bias, 128x128 tile (qkv). Bank-conflict-free B reads:
//     micro-tile cols {tx*4..+3} U {64+tx*4..+3}; Bs padded to 136 (row shift
//     8 banks, 16B-aligned). Per-output k-ascending fma chain -> bitwise same.
__global__ __launch_bounds__(256, 3) void gemm_bias128(const float* __restrict__ A,
                                                       const float* __restrict__ W,
                                                       const float* __restrict__ bias,
                                                       float* __restrict__ C,
                                                       int M, int N, int K) {
    const int BM = 128, BN = 128, BK = 16, TM = 8;
    __shared__ float As[BK][BM + 4];
    __shared__ float Bs[BK][136];
    int tid = threadIdx.x;
    int tx = tid & 15, ty = tid >> 4;
    int bm = blockIdx.x * BM, bn = blockIdx.y * BN;
    float acc[TM][8] = {};
    for (int k0 = 0; k0 < K; k0 += BK) {
#pragma unroll
        for (int it = 0; it < 2; ++it) {
            int i = it * 256 + tid;
            int row = i >> 2, kc = (i & 3) * 4;
            float4 v = *(const float4*)(A + (size_t)(bm + row) * K + k0 + kc);
            As[kc + 0][row] = v.x; As[kc + 1][row] = v.y;
            As[kc + 2][row] = v.z; As[kc + 3][row] = v.w;
        }
#pragma unroll
        for (int it = 0; it < 2; ++it) {
            int i = it * 256 + tid;
            int kr = i >> 5, nc = (i & 31) * 4;
            float4 v = *(const float4*)(W + (size_t)(k0 + kr) * N + bn + nc);
            *(float4*)&Bs[kr][nc] = v;
        }
        __syncthreads();
#pragma unroll
        for (int kk = 0; kk < BK; ++kk) {
            float a[TM], bb[8];
            const float4* ap = (const float4*)&As[kk][ty * TM];
            float4 a0 = ap[0], a1 = ap[1];
            a[0]=a0.x; a[1]=a0.y; a[2]=a0.z; a[3]=a0.w;
            a[4]=a1.x; a[5]=a1.y; a[6]=a1.z; a[7]=a1.w;
            float4 b0 = *(const float4*)&Bs[kk][tx * 4];
            float4 b1 = *(const float4*)&Bs[kk][64 + tx * 4];
            bb[0]=b0.x; bb[1]=b0.y; bb[2]=b0.z; bb[3]=b0.w;
            bb[4]=b1.x; bb[5]=b1.y; bb[6]=b1.z; bb[7]=b1.w;
#pragma unroll
            for (int i = 0; i < TM; ++i)
#pragma unroll
                for (int j = 0; j < 8; ++j)
                    acc[i][j] = fmaf(a[i], bb[j], acc[i][j]);
        }
        __syncthreads();
    }
#pragma unroll
    for (int i = 0; i < TM; ++i) {
        int row = bm + ty * TM + i;
        int col0 = bn + tx * 4;
        int col1 = bn + 64 + tx * 4;
        float4 o0 = make_float4(acc[i][0] + bias[col0 + 0], acc[i][1] + bias[col0 + 1],
                                acc[i][2] + bias[col0 + 2], acc[i][3] + bias[col0 + 3]);
        float4 o1 = make_float4(acc[i][4] + bias[col1 + 0], acc[i][5] + bias[col1 + 1],
                                acc[i][6] + bias[col1 + 2], acc[i][7] + bias[col1 + 3]);
        *(float4*)&C[(size_t)row * N + col0] = o0;
        *(float4*)&C[(size_t)row * N + col1] = o1;
    }
}

// ---------------------------------------------------------------------------
// 3b. fp32 GEMM + bias, 64x64 tile (proj; N=256 -> 1024 blocks = 4/CU).
__global__ __launch_bounds__(256, 4) void gemm_bias64(const float* __restrict__ A,
                                                      const float* __restrict__ W,
                                                      const float* __restrict__ bias,
                                                      float* __restrict__ C,
                                                      int M, int N, int K) {
    const int BM = 64, BN = 64, BK = 16;
    __shared__ float As[BK][BM + 4];
    __shared__ float Bs[BK][72];
    int tid = threadIdx.x;
    int tx = tid & 15, ty = tid >> 4;
    int bm = blockIdx.x * BM, bn = blockIdx.y * BN;
    float acc[4][4] = {};
    for (int k0 = 0; k0 < K; k0 += BK) {
        {
            int row = tid >> 2, kc = (tid & 3) * 4;
            float4 v = *(const float4*)(A + (size_t)(bm + row) * K + k0 + kc);
            As[kc + 0][row] = v.x; As[kc + 1][row] = v.y;
            As[kc + 2][row] = v.z; As[kc + 3][row] = v.w;
        }
        {
            int kr = tid >> 4, nc = (tid & 15) * 4;
            float4 v = *(const float4*)(W + (size_t)(k0 + kr) * N + bn + nc);
            *(float4*)&Bs[kr][nc] = v;
        }
        __syncthreads();
#pragma unroll
        for (int kk = 0; kk < BK; ++kk) {
            float4 av = *(const float4*)&As[kk][ty * 4];
            float4 bv = *(const float4*)&Bs[kk][tx * 4];
            float a[4] = {av.x, av.y, av.z, av.w};
            float bb[4] = {bv.x, bv.y, bv.z, bv.w};
#pragma unroll
            for (int i = 0; i < 4; ++i)
#pragma unroll
                for (int j = 0; j < 4; ++j)
                    acc[i][j] = fmaf(a[i], bb[j], acc[i][j]);
        }
        __syncthreads();
    }
#pragma unroll
    for (int i = 0; i < 4; ++i) {
        int row = bm + ty * 4 + i;
        int col = bn + tx * 4;
        float4 o = make_float4(acc[i][0] + bias[col + 0], acc[i][1] + bias[col + 1],
                               acc[i][2] + bias[col + 2], acc[i][3] + bias[col + 3]);
        *(float4*)&C[(size_t)row * N + col] = o;
    }
}

// ---------------------------------------------------------------------------
// 4. LIF over T
__global__ __launch_bounds__(256) void lif_kernel(const float* src, float* dst, size_t stride) {
    size_t i = ((size_t)blockIdx.x * blockDim.x + threadIdx.x) * 4;
    float v[4] = {0.f, 0.f, 0.f, 0.f};
    for (int t = 0; t < TT; ++t) {
        float4 xv4 = *(const float4*)(src + (size_t)t * stride + i);
        float xv[4] = {xv4.x, xv4.y, xv4.z, xv4.w};
        float sp[4];
#pragma unroll
        for (int j = 0; j < 4; ++j) {
            v[j] = v[j] + (xv[j] - v[j]) * 0.5f;
            bool fire = (v[j] >= 1.0f);
            sp[j] = fire ? 1.0f : 0.0f;
            v[j] = fire ? 0.0f : v[j];
        }
        *(float4*)(dst + (size_t)t * stride + i) = make_float4(sp[0], sp[1], sp[2], sp[3]);
    }
}

// ---------------------------------------------------------------------------
// 4b. pack Q/K spike bits
__global__ __launch_bounds__(256) void pack_kernel(const float* __restrict__ spk,
                                                   uint32_t* __restrict__ pk) {
    size_t g = (size_t)blockIdx.x * 256 + threadIdx.x;   // over 16384*512
    int row = (int)(g >> 9);
    int col = (int)(g & 511);
    float v = spk[(size_t)row * C3 + col];
    unsigned long long m = __ballot(v >= 0.5f);
    int lane = threadIdx.x & 63;
    if ((lane & 31) == 0)
        pk[(size_t)row * 16 + (col >> 5)] = (lane < 32) ? (uint32_t)m : (uint32_t)(m >> 32);
}

// ---------------------------------------------------------------------------
// 5. fused attention (sm + PV). Block = (t,b,n,hp,h): 1024 blocks, 128 threads.
//    Thread: softmax stats for q=tid (identical expr sequence to old attn_sm),
//    then PV for q in {qg,qg+64} x 16 d. V via global_load_lds DMA, 64-row
//    half-windows double-buffered with COUNTED vmcnt(4) (async across computes).
__global__ __launch_bounds__(128, 2) void attn_fused(const float* __restrict__ spk,
                                                     const uint32_t* __restrict__ pk,
                                                     const int* __restrict__ idxws,
                                                     float* __restrict__ out) {
    int bid = blockIdx.x;
    int h = bid & 1, hp = (bid >> 1) & 3, n = (bid >> 3) & 7, b = (bid >> 6) & 3, t = bid >> 8;
    __shared__ __align__(16) float Vlds[2][64][32];   // 2 x 8 KB half-window buffers
    __shared__ float ptab[33][WIN];                   // 16.9 KB
    __shared__ __align__(16) uint32_t kbs[4 * WIN];   // 2 KB (this h only)
    int tid = threadIdx.x;                            // 128 threads
    int qg = tid & 63, dh = tid >> 6;
    int lbase = (t * BB + b) * LL;

    const int* ip = idxws + (b * NWIN + n) * TOPKN;
    int sidx[TOPKN];
    sidx[0] = ip[0]; sidx[1] = ip[1]; sidx[2] = ip[2]; sidx[3] = ip[3];

    // stage gathered K bit-words (this h)
#pragma unroll 4
    for (int e = tid; e < 512; e += 128) {
        int w = e >> 7;
        int row = sidx[w] * WIN + (e & 127);
        kbs[e] = pk[(size_t)(lbase + row) * 16 + 8 + hp * 2 + h];
    }
    uint32_t qw0 = pk[(size_t)(lbase + n * WIN + qg) * 16 + hp * 2 + h];
    uint32_t qw1 = pk[(size_t)(lbase + n * WIN + qg + 64) * 16 + hp * 2 + h];
    uint32_t qwt = pk[(size_t)(lbase + n * WIN + tid) * 16 + hp * 2 + h];
    __syncthreads();   // kbs visible

    // V DMA geometry (same as proven v12): per-lane global src, LDS = base+lane*16
    const float* vsrc = spk + (size_t)lbase * C3 + 512 + hp * 64 + h * 32
                        + (size_t)(tid >> 3) * C3 + (tid & 7) * 4;
    int wvoff = (tid >> 6) * 1024;   // wave-uniform

#define STAGE_HALF(hw_)                                                              \
    do {                                                                             \
        int hw = (hw_);                                                              \
        const float* src = vsrc + (size_t)sidx[hw >> 1] * (WIN * C3)                 \
                                + (size_t)(hw & 1) * 64 * C3;                        \
        char* lbasep = (char*)(&Vlds[hw & 1][0][0]) + wvoff;                         \
        _Pragma("unroll")                                                            \
        for (int it = 0; it < 4; ++it) {                                             \
            __builtin_amdgcn_global_load_lds(                                        \
                (const __attribute__((address_space(1))) void*)(src + (size_t)it * 16 * C3), \
                (__attribute__((address_space(3))) void*)(lbasep + it * 2048),       \
                16, 0, 0);                                                           \
        }                                                                            \
    } while (0)

    STAGE_HALF(0);
    STAGE_HALF(1);

    // ---- fused softmax stats for q = tid (hidden under the in-flight DMAs)
    const float ALPHA_SC = 0.17677669529663687f;   // hd^-0.5
    const uint4* kb4 = (const uint4*)kbs;
    int smax = 0;
#pragma unroll 8
    for (int k4 = 0; k4 < 128; ++k4) {
        uint4 w4 = kb4[k4];
        smax = max(smax, __popc(qwt & w4.x));
        smax = max(smax, __popc(qwt & w4.y));
        smax = max(smax, __popc(qwt & w4.z));
        smax = max(smax, __popc(qwt & w4.w));
    }
    float am = __fmul_rn((float)smax, ALPHA_SC);
    float Z = 0.0f;
#pragma unroll 4
    for (int k4 = 0; k4 < 128; ++k4) {
        uint4 w4 = kb4[k4];
        Z += expf(__fsub_rn(__fmul_rn((float)__popc(qwt & w4.x), ALPHA_SC), am));
        Z += expf(__fsub_rn(__fmul_rn((float)__popc(qwt & w4.y), ALPHA_SC), am));
        Z += expf(__fsub_rn(__fmul_rn((float)__popc(qwt & w4.z), ALPHA_SC), am));
        Z += expf(__fsub_rn(__fmul_rn((float)__popc(qwt & w4.w), ALPHA_SC), am));
    }
    for (int s = 0; s <= 32; ++s)
        ptab[s][tid] = expf(__fsub_rn(__fmul_rn((float)s, ALPHA_SC), am)) / Z;

    float acc0[16], acc1[16];
#pragma unroll
    for (int d = 0; d < 16; ++d) { acc0[d] = 0.0f; acc1[d] = 0.0f; }

    asm volatile("s_waitcnt vmcnt(4)" ::: "memory");   // half0 done; half1 in flight
    __syncthreads();                                   // half0 + ptab visible

#pragma unroll
    for (int hw = 0; hw < 8; ++hw) {
        // compute half hw: 16 groups of 4 rows, 2-row load batches, ascending k
        const uint4* kw4 = kb4 + hw * 16;
        const float* vb = &Vlds[hw & 1][0][dh * 16];
#pragma unroll 2
        for (int g = 0; g < 16; ++g) {
            uint4 kw = kw4[g];
            const float* pr = vb + g * 128;
#pragma unroll
            for (int jp = 0; jp < 2; ++jp) {
                uint32_t ka = (jp == 0) ? kw.x : kw.z;
                uint32_t kb_ = (jp == 0) ? kw.y : kw.w;
                float Pa0 = ptab[__popc(qw0 & ka)][qg];
                float Pa1 = ptab[__popc(qw1 & ka)][qg + 64];
                float Pb0 = ptab[__popc(qw0 & kb_)][qg];
                float Pb1 = ptab[__popc(qw1 & kb_)][qg + 64];
                const float4* va = (const float4*)(pr + jp * 64);
                const float4* vbp = (const float4*)(pr + jp * 64 + 32);
                float4 a0 = va[0], a1 = va[1], a2 = va[2], a3 = va[3];
                float4 b0 = vbp[0], b1 = vbp[1], b2 = vbp[2], b3 = vbp[3];
                // row a (k even) then row b (k odd): per-chain ascending k
                acc0[ 0] = fmaf(Pa0, a0.x, acc0[ 0]);  acc1[ 0] = fmaf(Pa1, a0.x, acc1[ 0]);
                acc0[ 1] = fmaf(Pa0, a0.y, acc0[ 1]);  acc1[ 1] = fmaf(Pa1, a0.y, acc1[ 1]);
                acc0[ 2] = fmaf(Pa0, a0.z, acc0[ 2]);  acc1[ 2] = fmaf(Pa1, a0.z, acc1[ 2]);
                acc0[ 3] = fmaf(Pa0, a0.w, acc0[ 3]);  acc1[ 3] = fmaf(Pa1, a0.w, acc1[ 3]);
                acc0[ 4] = fmaf(Pa0, a1.x, acc0[ 4]);  acc1[ 4] = fmaf(Pa1, a1.x, acc1[ 4]);
                acc0[ 5] = fmaf(Pa0, a1.y, acc0[ 5]);  acc1[ 5] = fmaf(Pa1, a1.y, acc1[ 5]);
                acc0[ 6] = fmaf(Pa0, a1.z, acc0[ 6]);  acc1[ 6] = fmaf(Pa1, a1.z, acc1[ 6]);
                acc0[ 7] = fmaf(Pa0, a1.w, acc0[ 7]);  acc1[ 7] = fmaf(Pa1, a1.w, acc1[ 7]);
                acc0[ 8] = fmaf(Pa0, a2.x, acc0[ 8]);  acc1[ 8] = fmaf(Pa1, a2.x, acc1[ 8]);
                acc0[ 9] = fmaf(Pa0, a2.y, acc0[ 9]);  acc1[ 9] = fmaf(Pa1, a2.y, acc1[ 9]);
                acc0[10] = fmaf(Pa0, a2.z, acc0[10]);  acc1[10] = fmaf(Pa1, a2.z, acc1[10]);
                acc0[11] = fmaf(Pa0, a2.w, acc0[11]);  acc1[11] = fmaf(Pa1, a2.w, acc1[11]);
                acc0[12] = fmaf(Pa0, a3.x, acc0[12]);  acc1[12] = fmaf(Pa1, a3.x, acc1[12]);
                acc0[13] = fmaf(Pa0, a3.y, acc0[13]);  acc1[13] = fmaf(Pa1, a3.y, acc1[13]);
                acc0[14] = fmaf(Pa0, a3.z, acc0[14]);  acc1[14] = fmaf(Pa1, a3.z, acc1[14]);
                acc0[15] = fmaf(Pa0, a3.w, acc0[15]);  acc1[15] = fmaf(Pa1, a3.w, acc1[15]);
                acc0[ 0] = fmaf(Pb0, b0.x, acc0[ 0]);  acc1[ 0] = fmaf(Pb1, b0.x, acc1[ 0]);
                acc0[ 1] = fmaf(Pb0, b0.y, acc0[ 1]);  acc1[ 1] = fmaf(Pb1, b0.y, acc1[ 1]);
                acc0[ 2] = fmaf(Pb0, b0.z, acc0[ 2]);  acc1[ 2] = fmaf(Pb1, b0.z, acc1[ 2]);
                acc0[ 3] = fmaf(Pb0, b0.w, acc0[ 3]);  acc1[ 3] = fmaf(Pb1, b0.w, acc1[ 3]);
                acc0[ 4] = fmaf(Pb0, b1.x, acc0[ 4]);  acc1[ 4] = fmaf(Pb1, b1.x, acc1[ 4]);
                acc0[ 5] = fmaf(Pb0, b1.y, acc0[ 5]);  acc1[ 5] = fmaf(Pb1, b1.y, acc1[ 5]);
                acc0[ 6] = fmaf(Pb0, b1.z, acc0[ 6]);  acc1[ 6] = fmaf(Pb1, b1.z, acc1[ 6]);
                acc0[ 7] = fmaf(Pb0, b1.w, acc0[ 7]);  acc1[ 7] = fmaf(Pb1, b1.w, acc1[ 7]);
                acc0[ 8] = fmaf(Pb0, b2.x, acc0[ 8]);  acc1[ 8] = fmaf(Pb1, b2.x, acc1[ 8]);
                acc0[ 9] = fmaf(Pb0, b2.y, acc0[ 9]);  acc1[ 9] = fmaf(Pb1, b2.y, acc1[ 9]);
                acc0[10] = fmaf(Pb0, b2.z, acc0[10]);  acc1[10] = fmaf(Pb1, b2.z, acc1[10]);
                acc0[11] = fmaf(Pb0, b2.w, acc0[11]);  acc1[11] = fmaf(Pb1, b2.w, acc1[11]);
                acc0[12] = fmaf(Pb0, b3.x, acc0[12]);  acc1[12] = fmaf(Pb1, b3.x, acc1[12]);
                acc0[13] = fmaf(Pb0, b3.y, acc0[13]);  acc1[13] = fmaf(Pb1, b3.y, acc1[13]);
                acc0[14] = fmaf(Pb0, b3.z, acc0[14]);  acc1[14] = fmaf(Pb1, b3.z, acc1[14]);
                acc0[15] = fmaf(Pb0, b3.w, acc0[15]);  acc1[15] = fmaf(Pb1, b3.w, acc1[15]);
            }
        }

        if (hw < 7) {
            __syncthreads();              // all waves done reading buf[hw&1]
            if (hw < 6) {
                STAGE_HALF(hw + 2);       // refill buf[hw&1]
                asm volatile("s_waitcnt vmcnt(4)" ::: "memory");  // drain S(hw+1)
            } else {
                asm volatile("s_waitcnt vmcnt(0)" ::: "memory");  // drain S(7)
            }
            __syncthreads();              // half hw+1 visible to all waves
        }
    }
#undef STAGE_HALF

    size_t ob0 = (size_t)(lbase + n * WIN + qg) * CC + (hp * 2 + h) * 32 + dh * 16;
    size_t ob1 = ob0 + (size_t)64 * CC;
#pragma unroll
    for (int d = 0; d < 16; ++d) out[ob0 + d] = acc0[d];
#pragma unroll
    for (int d = 0; d < 16; ++d) out[ob1 + d] = acc1[d];
}

// ---------------------------------------------------------------------------
extern "C" void kernel_launch(void* const* d_in, const int* in_sizes, int n_in,
                              void* d_out, int out_size, void* d_ws, size_t ws_size,
                              hipStream_t stream) {
    const float* x      = (const float*)d_in[0];
    const float* w_qkv  = (const float*)d_in[1];
    const float* b_qkv  = (const float*)d_in[2];
    const float* w_proj = (const float*)d_in[3];
    const float* b_proj = (const float*)d_in[4];
    float* ws = (float*)d_ws;

    float* qkv      = ws;                 // 12582912 floats [T,B,L,3C] (spikes after LIF)
    float* attn_out = ws + 12582912;      // 4194304 floats [T,B,L,C]
    float* proj     = ws + 16777216;      // 4194304 floats [T,B,L,C]
    uint32_t* pkb   = (uint32_t*)proj;    // 262144 u32: aliases proj (dead before gemm_proj)
    float* region   = ws + 20971520;      // 8192 floats
    int*   idxp     = (int*)(ws + 20979712);  // 128 ints
    float* outp     = (float*)d_out;

    region_kernel<<<dim3(BB * NWIN), dim3(256), 0, stream>>>(x, region);
    route_kernel<<<dim3(BB), dim3(64), 0, stream>>>(region, idxp);
    gemm_bias128<<<dim3(128, 6), dim3(256), 0, stream>>>(x, w_qkv, b_qkv, qkv,
                                                         TT * BB * LL, C3, CC);
    lif_kernel<<<dim3(3072), dim3(256), 0, stream>>>(qkv, qkv, (size_t)BB * LL * C3);
    pack_kernel<<<dim3(32768), dim3(256), 0, stream>>>(qkv, pkb);
    attn_fused<<<dim3(TT * BB * NWIN * 4 * 2), dim3(128), 0, stream>>>(qkv, pkb, idxp, attn_out);
    gemm_bias64<<<dim3(256, 4), dim3(256), 0, stream>>>(attn_out, w_proj, b_proj, proj,
                                                        TT * BB * LL, CC, CC);
    lif_kernel<<<dim3(1024), dim3(256), 0, stream>>>(proj, outp, (size_t)BB * LL * CC);
}